// Round 1
// baseline (267.092 us; speedup 1.0000x reference)
//
#include <hip/hip_runtime.h>

// P2B_XCorr: B=8, F=128, M=256, N=1024, H=64, O=128. fp32 I/O.
// R9 = R8 + k_main occupancy doubling:
//   - grid (32,8,2) -> (64,8,2): 16 n-cols/block, 4 waves split m 4-ways
//     (m = ms*128 + mc*4 + w, mc=0..31). 4 blocks/CU = 4 waves/SIMD (was 2),
//     so one wave's VALU h1-build/pack overlaps another's MFMA.
//   - cross-wave combine: waves 1..3 park p in redS, wave 0 4-way max + store.
//     No extra P partials -> no ws growth.
//   - W2/W3 folded weights prepacked to f16 [g][k] in k_prep (same (_Float16)
//     cast as the old in-kernel convert -> bit-identical), so k_main setup is
//     16 b128 loads instead of 128 scalar f32 loads + converts.
// Frag layouts (HW-verified): A[m=lane&15][k=quad*8+j], B[k=quad*8+j][n=lane&15],
// D[row=quad*4+reg][col=lane&15].

#define BB 8
#define FF 128
#define MM 256
#define NN 1024
#define HH 64
#define OO 128
#define BN_EPS 1e-5f
#define COS_EPS 1e-8f

// ws layout (float offsets); total 2,251,008 floats = 8.59 MiB (proven envelope)
#define WS_U     0
#define WS_C2    64
#define WS_C3    128
#define WS_CC1   192
#define WS_W2H   256          // f16 [64][64] folded a2*W2 (2048 float slots)
#define WS_W3H   2304         // f16 [64][64] folded a3*W3 (2048 float slots)
#define WS_WC1F  8448
#define WS_A1    12544        // f16 A1H[b][m][64]
#define WS_NT    143616       // [b][m] fp32 (NS contiguous after)
#define WS_NS    145664       // [b][n] fp32
#define WS_COSH  153856       // f16 cos[b][m][n]
#define WS_P     1202432      // fp32 partials [2][b][n][64]
#define PS       524288

typedef _Float16 half2v __attribute__((ext_vector_type(2)));
typedef _Float16 half8  __attribute__((ext_vector_type(8)));
typedef __attribute__((ext_vector_type(4))) float f32x4;

__device__ __forceinline__ unsigned int pkh2(float a, float b){
  auto h = __builtin_amdgcn_cvt_pkrtz(a, b);
  return __builtin_bit_cast(unsigned int, h);
}
__device__ __forceinline__ half2v u2h(unsigned int u){
  return __builtin_bit_cast(half2v, u);
}
__device__ __forceinline__ unsigned int h2u(half2v v){
  return __builtin_bit_cast(unsigned int, v);
}
__device__ __forceinline__ unsigned int relu2(unsigned int d){
  half2v v = __builtin_elementwise_max(u2h(d), (half2v){(_Float16)0, (_Float16)0});
  return h2u(v);
}
__device__ __forceinline__ unsigned int bh1(unsigned int up, half2v c, unsigned int ap){
  half2v v = __builtin_elementwise_fma(u2h(up), c, u2h(ap));
  v = __builtin_elementwise_max(v, (half2v){(_Float16)0, (_Float16)0});
  return h2u(v);
}
__device__ __forceinline__ float dot4(float4 a, float4 b, float acc){
  acc = fmaf(a.x, b.x, acc); acc = fmaf(a.y, b.y, acc);
  acc = fmaf(a.z, b.z, acc); acc = fmaf(a.w, b.w, acc);
  return acc;
}

// ---------------- K1: prep (role-split: a1 | norms | fold) ----------------
__global__ __launch_bounds__(256) void k_prep(const float* t_, const float* s_,
    const float* W1, const float* W2, const float* W3, const float* Wc1,
    const float* g1, const float* b1, const float* m1, const float* v1,
    const float* g2, const float* b2, const float* m2, const float* v2,
    const float* g3, const float* b3, const float* m3, const float* v3,
    const float* gc1,const float* bc1,const float* mc1,const float* vc1,
    float* ws){
  __shared__ float W1s[64][133];
  int t = threadIdx.x;
  int bx = blockIdx.x;
  if (bx < 256){
    // ---- A1H[b][m][h] (f16) ----
    int b = bx >> 5, m0 = (bx & 31)*8;
    for (int idx = t; idx < 8192; idx += 256){
      int h = idx >> 7, f = idx & 127;
      W1s[h][f] = W1[h*129 + 1 + f];
    }
    __syncthreads();
    int h = t & 63, mg = t >> 6;
    const float* tp = t_ + (size_t)b*FF*MM + m0 + mg*2;
    float acc0 = 0.f, acc1 = 0.f;
    for (int f = 0; f < FF; f++){
      float wv = W1s[h][f];
      float2 tv = *(const float2*)&tp[(size_t)f*MM];
      acc0 = fmaf(wv, tv.x, acc0); acc1 = fmaf(wv, tv.y, acc1);
    }
    float a1 = g1[h] / sqrtf(v1[h] + BN_EPS);
    float c1 = b1[h] - a1*m1[h];
    unsigned short* dst = (unsigned short*)(ws + WS_A1) + ((size_t)(b*MM + m0 + mg*2))*64 + h;
    dst[0]  = (unsigned short)(pkh2(fmaf(a1, acc0, c1), 0.f) & 0xFFFFu);
    dst[64] = (unsigned short)(pkh2(fmaf(a1, acc1, c1), 0.f) & 0xFFFFu);
  } else if (bx < 416){
    // ---- norms ----
    __shared__ float red[4][64];
    int x = t & 63, fq = t >> 6;
    int idx = (bx - 256)*64 + x;
    const float* ptr; size_t stride;
    if (idx < BB*MM){
      int b = idx >> 8, m = idx & 255;
      ptr = t_ + (size_t)b*FF*MM + m; stride = MM;
    } else {
      int j = idx - BB*MM;
      int b = j >> 10, n = j & 1023;
      ptr = s_ + (size_t)b*FF*NN + n; stride = NN;
    }
    float acc = 0.f;
    for (int f = fq*32; f < fq*32 + 32; f++){
      float v = ptr[(size_t)f*stride]; acc = fmaf(v, v, acc);
    }
    red[fq][x] = acc;
    __syncthreads();
    if (fq == 0)
      ws[WS_NT + idx] = sqrtf(red[0][x] + red[1][x] + red[2][x] + red[3][x]);
  } else {
    // ---- fold ----
    if (t < 64){
      float a1 = g1[t] / sqrtf(v1[t] + BN_EPS);
      ws[WS_U + t]   = a1 * W1[t*129];
      float a2 = g2[t] / sqrtf(v2[t] + BN_EPS);
      ws[WS_C2 + t]  = b2[t] - a2*m2[t];
      float a3 = g3[t] / sqrtf(v3[t] + BN_EPS);
      ws[WS_C3 + t]  = b3[t] - a3*m3[t];
      float ac = gc1[t] / sqrtf(vc1[t] + BN_EPS);
      ws[WS_CC1 + t] = bc1[t] - ac*mc1[t];
    }
    unsigned short* w2h = (unsigned short*)(ws + WS_W2H);
    unsigned short* w3h = (unsigned short*)(ws + WS_W3H);
    for (int i = t; i < 4096; i += 256){
      int g = i >> 6;
      float a2 = g2[g] / sqrtf(v2[g] + BN_EPS);
      w2h[i] = __builtin_bit_cast(unsigned short, (_Float16)(a2 * W2[i]));
      float a3 = g3[g] / sqrtf(v3[g] + BN_EPS);
      w3h[i] = __builtin_bit_cast(unsigned short, (_Float16)(a3 * W3[i]));
      float ac = gc1[g] / sqrtf(vc1[g] + BN_EPS);
      ws[WS_WC1F + i] = ac * Wc1[i];
    }
  }
}

// ---------------- K2: cos via f16 MFMA. tile 64m x 64n ----------------
__global__ __launch_bounds__(256) void k_cos(const float* t_, const float* s_, float* ws){
  __shared__ __align__(16) unsigned short tS[64][136];
  __shared__ __align__(16) unsigned short sS[64][136];
  __shared__ float ntS[64], nsS[64];
  int t = threadIdx.x;
  int lane = t & 63, w = t >> 6;
  int ln15 = lane & 15, quad = lane >> 4;
  int m0 = blockIdx.x*64, n0 = blockIdx.y*64, b = blockIdx.z;
  {
    int x = t & 63;
    const float* tb = t_ + (size_t)b*FF*MM + m0 + x;
    const float* sb = s_ + (size_t)b*FF*NN + n0 + x;
    #pragma unroll
    for (int k = 0; k < 16; k++){
      int fp = w*16 + k;
      *(unsigned int*)&tS[x][2*fp] = pkh2(tb[(size_t)(2*fp)*MM], tb[(size_t)(2*fp+1)*MM]);
      *(unsigned int*)&sS[x][2*fp] = pkh2(sb[(size_t)(2*fp)*NN], sb[(size_t)(2*fp+1)*NN]);
    }
    if (t < 64) ntS[t] = ws[WS_NT + b*MM + m0 + t];
    else if (t < 128) nsS[t-64] = ws[WS_NS + b*NN + n0 + (t-64)];
  }
  __syncthreads();
  half8 A4[4];
  #pragma unroll
  for (int kc = 0; kc < 4; kc++)
    A4[kc] = *(const half8*)&tS[w*16 + ln15][kc*32 + quad*8];
  float4 nt4 = *(const float4*)&ntS[w*16 + quad*4];
  unsigned short* cosw = (unsigned short*)(ws + WS_COSH);
  #pragma unroll
  for (int ns = 0; ns < 4; ns++){
    f32x4 acc = (f32x4){0.f,0.f,0.f,0.f};
    #pragma unroll
    for (int kc = 0; kc < 4; kc++){
      half8 B4 = *(const half8*)&sS[ns*16 + ln15][kc*32 + quad*8];
      acc = __builtin_amdgcn_mfma_f32_16x16x32_f16(A4[kc], B4, acc, 0, 0, 0);
    }
    float nsv = nsS[ns*16 + ln15];
    int n = n0 + ns*16 + ln15;
    #pragma unroll
    for (int r = 0; r < 4; r++){
      int m = m0 + w*16 + quad*4 + r;
      float denom = fmaxf(nt4[r]*nsv, COS_EPS);
      float c = acc[r] * __builtin_amdgcn_rcpf(denom);
      cosw[(size_t)(b*MM + m)*NN + n] = (unsigned short)(pkh2(c, 0.f) & 0xFFFFu);
    }
  }
}

// ---------------- K3: main. grid (64,8,2), 4 waves; wave w: m = ms*128 + mc*4 + w ----------------
__global__ __launch_bounds__(256, 4) void k_main(const float* ws, float* Pp){
  __shared__ __align__(16) unsigned short h2W[4][16][72];  // per-wave [x16][g64+pad]
  __shared__ __align__(16) float redS[3][16][68];          // parked partials (waves 1..3)
  int t = threadIdx.x;
  int lane = t & 63, w = t >> 6;
  int ln15 = lane & 15, quad = lane >> 4;
  int b = blockIdx.y;
  int n0 = blockIdx.x * 16;
  int ms = blockIdx.z;

  // weight A-frags (prepacked f16 [g][k]) + bias C-vectors
  const unsigned short* w2h = (const unsigned short*)(ws + WS_W2H);
  const unsigned short* w3h = (const unsigned short*)(ws + WS_W3H);
  half8 W2A[4][2], W3A[4][2];
  f32x4 c2v[4], c3v[4];
  #pragma unroll
  for (int rt = 0; rt < 4; rt++){
    int g = rt*16 + ln15;
    #pragma unroll
    for (int kk = 0; kk < 2; kk++){
      W2A[rt][kk] = *(const half8*)&w2h[g*64 + kk*32 + quad*8];
      W3A[rt][kk] = *(const half8*)&w3h[g*64 + kk*32 + quad*8];
    }
    float4 cb2 = *(const float4*)&ws[WS_C2 + rt*16 + quad*4];
    float4 cb3 = *(const float4*)&ws[WS_C3 + rt*16 + quad*4];
    c2v[rt] = (f32x4){cb2.x, cb2.y, cb2.z, cb2.w};
    c3v[rt] = (f32x4){cb3.x, cb3.y, cb3.z, cb3.w};
  }
  // u[h] packed pairs for this lane's h-chunks
  unsigned int upk[2][4];
  #pragma unroll
  for (int kk = 0; kk < 2; kk++){
    float4 ua = *(const float4*)&ws[WS_U + kk*32 + quad*8];
    float4 ub = *(const float4*)&ws[WS_U + kk*32 + quad*8 + 4];
    upk[kk][0] = pkh2(ua.x, ua.y); upk[kk][1] = pkh2(ua.z, ua.w);
    upk[kk][2] = pkh2(ub.x, ub.y); upk[kk][3] = pkh2(ub.z, ub.w);
  }
  const unsigned short* A1H = (const unsigned short*)(ws + WS_A1) + (size_t)b*MM*64;
  int n = n0 + ln15;                                // this lane's n (shared by all waves)
  const unsigned short* cosP = (const unsigned short*)(ws + WS_COSH)
                               + (size_t)b*MM*NN + n;
  unsigned short* h2w = &h2W[w][0][0];

  f32x4 p[4];
  #pragma unroll
  for (int rt = 0; rt < 4; rt++) p[rt] = (f32x4){0.f,0.f,0.f,0.f};

  int m0i = ms*128 + w;
  unsigned int cu = cosP[(size_t)m0i*NN];
  uint4 a1a = *(const uint4*)&A1H[(size_t)m0i*64 + quad*8];
  uint4 a1b = *(const uint4*)&A1H[(size_t)m0i*64 + 32 + quad*8];

  for (int mc = 0; mc < 32; mc++){
    // prefetch next mc
    int mN = ms*128 + (mc < 31 ? (mc + 1) : 31)*4 + w;
    unsigned int cuN = cosP[(size_t)mN*NN];
    uint4 a1aN = *(const uint4*)&A1H[(size_t)mN*64 + quad*8];
    uint4 a1bN = *(const uint4*)&A1H[(size_t)mN*64 + 32 + quad*8];

    unsigned int cd = cu | (cu << 16);
    half2v ch = u2h(cd);
    uint4 q0, q1;
    q0.x = bh1(upk[0][0], ch, a1a.x); q0.y = bh1(upk[0][1], ch, a1a.y);
    q0.z = bh1(upk[0][2], ch, a1a.z); q0.w = bh1(upk[0][3], ch, a1a.w);
    q1.x = bh1(upk[1][0], ch, a1b.x); q1.y = bh1(upk[1][1], ch, a1b.y);
    q1.z = bh1(upk[1][2], ch, a1b.z); q1.w = bh1(upk[1][3], ch, a1b.w);
    half8 b0h = __builtin_bit_cast(half8, q0);
    half8 b1h = __builtin_bit_cast(half8, q1);

    // layer 2
    f32x4 acc[4];
    #pragma unroll
    for (int rt = 0; rt < 4; rt++){
      acc[rt] = __builtin_amdgcn_mfma_f32_16x16x32_f16(W2A[rt][0], b0h, c2v[rt], 0, 0, 0);
      acc[rt] = __builtin_amdgcn_mfma_f32_16x16x32_f16(W2A[rt][1], b1h, acc[rt], 0, 0, 0);
    }
    // relu + pack + h2 transpose write (g = rt*16 + quad*4 + r, row x = ln15)
    #pragma unroll
    for (int rt = 0; rt < 4; rt++){
      uint2 vv;
      vv.x = relu2(pkh2(acc[rt][0], acc[rt][1]));
      vv.y = relu2(pkh2(acc[rt][2], acc[rt][3]));
      *(uint2*)&h2w[ln15*72 + rt*16 + quad*4] = vv;
    }
    __asm__ volatile("s_waitcnt lgkmcnt(0)" ::: "memory");
    half8 e0 = *(const half8*)&h2w[ln15*72 + quad*8];
    half8 e1 = *(const half8*)&h2w[ln15*72 + 32 + quad*8];
    // layer 3 + running max
    #pragma unroll
    for (int rt = 0; rt < 4; rt++){
      f32x4 a3 = __builtin_amdgcn_mfma_f32_16x16x32_f16(W3A[rt][0], e0, c3v[rt], 0, 0, 0);
      a3 = __builtin_amdgcn_mfma_f32_16x16x32_f16(W3A[rt][1], e1, a3, 0, 0, 0);
      #pragma unroll
      for (int r = 0; r < 4; r++) p[rt][r] = fmaxf(p[rt][r], a3[r]);
    }
    cu = cuN; a1a = a1aN; a1b = a1bN;
  }

  // 4-way cross-wave max combine: waves 1..3 park, wave 0 merges + stores.
  __syncthreads();
  if (w >= 1){
    #pragma unroll
    for (int rt = 0; rt < 4; rt++){
      f32x4 v = p[rt];
      *(float4*)&redS[w-1][ln15][rt*16 + quad*4] = make_float4(v[0], v[1], v[2], v[3]);
    }
  }
  __syncthreads();
  if (w == 0){
    float* Pb = Pp + (size_t)ms*PS + ((size_t)(b*NN + n) << 6);
    #pragma unroll
    for (int rt = 0; rt < 4; rt++){
      float4 o1 = *(const float4*)&redS[0][ln15][rt*16 + quad*4];
      float4 o2 = *(const float4*)&redS[1][ln15][rt*16 + quad*4];
      float4 o3 = *(const float4*)&redS[2][ln15][rt*16 + quad*4];
      float4 r4;
      r4.x = fmaxf(fmaxf(p[rt][0], o1.x), fmaxf(o2.x, o3.x));
      r4.y = fmaxf(fmaxf(p[rt][1], o1.y), fmaxf(o2.y, o3.y));
      r4.z = fmaxf(fmaxf(p[rt][2], o1.z), fmaxf(o2.z, o3.z));
      r4.w = fmaxf(fmaxf(p[rt][3], o1.w), fmaxf(o2.w, o3.w));
      *(float4*)&Pb[rt*16 + quad*4] = r4;
    }
  }
}

// ---------------- K4: tail (max 2 partials, Wc1f/relu, Wc2+bias) fp32 ----------------
__global__ __launch_bounds__(256) void k_tail(const float* Wc2, const float* bc2,
                                              const float* ws, float* out){
  __shared__ float WT[64][68];
  __shared__ float pT[32][68];
  __shared__ float cS[32][68];
  int t = threadIdx.x;
  int n0 = blockIdx.x * 32;
  int b = blockIdx.y;
  for (int i = t; i < 4096; i += 256) WT[i >> 6][i & 63] = ws[WS_WC1F + i];
  const float* P0 = ws + WS_P + ((size_t)(b*NN + n0) << 6);
  const float* P1 = P0 + PS;
  for (int i = t; i < 2048; i += 256) pT[i >> 6][i & 63] = fmaxf(P0[i], P1[i]);
  __syncthreads();
  {
    int n = t & 31, q = t >> 5;
    for (int k = 0; k < 8; k++){
      int g = q*8 + k;
      float acc = ws[WS_CC1 + g];
      for (int hs = 0; hs < 64; hs += 4){
        float4 wv = *(const float4*)&WT[g][hs];
        float4 pv = *(const float4*)&pT[n][hs];
        acc = dot4(wv, pv, acc);
      }
      cS[n][g] = fmaxf(acc, 0.f);
    }
  }
  __syncthreads();
  {
    int o = t & 127, hf = t >> 7;
    float bco = bc2[o];
    float accO[16];
    #pragma unroll
    for (int i = 0; i < 16; i++) accO[i] = bco;
    for (int hs = 0; hs < 64; hs += 4){
      float4 w4 = *(const float4*)&Wc2[o*64 + hs];
      #pragma unroll
      for (int i = 0; i < 16; i++){
        float4 cv = *(const float4*)&cS[hf*16 + i][hs];
        accO[i] = dot4(w4, cv, accO[i]);
      }
    }
    #pragma unroll
    for (int i = 0; i < 16; i++)
      out[((size_t)(b*OO + o))*NN + n0 + hf*16 + i] = accO[i];
  }
}

extern "C" void kernel_launch(void* const* d_in, const int* in_sizes, int n_in,
                              void* d_out, int out_size, void* d_ws, size_t ws_size,
                              hipStream_t stream){
  (void)in_sizes; (void)n_in; (void)out_size; (void)ws_size;
  const float* t_  = (const float*)d_in[0];
  const float* s_  = (const float*)d_in[1];
  const float* W1  = (const float*)d_in[2];
  const float* W2  = (const float*)d_in[3];
  const float* W3  = (const float*)d_in[4];
  const float* Wc1 = (const float*)d_in[5];
  const float* Wc2 = (const float*)d_in[6];
  const float* bc2 = (const float*)d_in[7];
  const float* g1 = (const float*)d_in[8],  *b1 = (const float*)d_in[9],
             * m1 = (const float*)d_in[10], *v1 = (const float*)d_in[11];
  const float* g2 = (const float*)d_in[12], *b2 = (const float*)d_in[13],
             * m2 = (const float*)d_in[14], *v2 = (const float*)d_in[15];
  const float* g3 = (const float*)d_in[16], *b3 = (const float*)d_in[17],
             * m3 = (const float*)d_in[18], *v3 = (const float*)d_in[19];
  const float* gc1 = (const float*)d_in[20], *bc1 = (const float*)d_in[21],
             * mc1 = (const float*)d_in[22], *vc1 = (const float*)d_in[23];
  float* ws = (float*)d_ws;
  float* out = (float*)d_out;

  k_prep<<<417, 256, 0, stream>>>(t_, s_, W1, W2, W3, Wc1,
      g1,b1,m1,v1, g2,b2,m2,v2, g3,b3,m3,v3, gc1,bc1,mc1,vc1, ws);
  k_cos<<<dim3(4, 16, 8), 256, 0, stream>>>(t_, s_, ws);
  k_main<<<dim3(64, 8, 2), 256, 0, stream>>>(ws, ws + WS_P);
  k_tail<<<dim3(32, 8), 256, 0, stream>>>(Wc2, bc2, ws, out);
}

// Round 2
// 198.879 us; speedup vs baseline: 1.3430x; 1.3430x over previous
//
#include <hip/hip_runtime.h>

// P2B_XCorr: B=8, F=128, M=256, N=1024, H=64, O=128. fp32 I/O.
// R10 = g-split k_main (R9 post-mortem: launch_bounds(256,4) capped unified
//   VGPR+AGPR at 128; old per-wave live set ~180 -> ~50 regs spilled in-loop ->
//   247 MB scratch FETCH/dispatch. Fix: shrink the live set, not the bound.)
//   - grid (64,8,2), 4 waves. ALL waves process the same m per iter; wave w owns
//     g-slice [16w,16w+16) for BOTH layers: W2A+W3A = 16 regs (was 64).
//   - c3 deferred: max-over-m commutes with +const; seed layer-3 acc with 0,
//     apply relu(p + c3) at the store. p seeded at -3e38.
//   - h2 transpose via ONE shared [16n][64g] LDS tile, double-buffered,
//     exactly one __syncthreads per m (prev-buffer reads precede this barrier
//     in program order -> no WAR race).
//   - no end-of-kernel cross-wave reduction: wave w stores its own g-slice.
//   Estimated live set ~90 unified regs -> fits (256,4): 4 blocks/CU, no tail.
// Frag layouts (HW-verified): A[m=lane&15][k=quad*8+j], B[k=quad*8+j][n=lane&15],
// D[row=quad*4+reg][col=lane&15].

#define BB 8
#define FF 128
#define MM 256
#define NN 1024
#define HH 64
#define OO 128
#define BN_EPS 1e-5f
#define COS_EPS 1e-8f

// ws layout (float offsets); total 2,251,008 floats = 8.59 MiB (proven envelope)
#define WS_U     0
#define WS_C2    64
#define WS_C3    128
#define WS_CC1   192
#define WS_W2H   256          // f16 [64][64] folded a2*W2 (2048 float slots)
#define WS_W3H   2304         // f16 [64][64] folded a3*W3 (2048 float slots)
#define WS_WC1F  8448
#define WS_A1    12544        // f16 A1H[b][m][64]
#define WS_NT    143616       // [b][m] fp32 (NS contiguous after)
#define WS_NS    145664       // [b][n] fp32
#define WS_COSH  153856       // f16 cos[b][m][n]
#define WS_P     1202432      // fp32 partials [2][b][n][64]
#define PS       524288

typedef _Float16 half2v __attribute__((ext_vector_type(2)));
typedef _Float16 half8  __attribute__((ext_vector_type(8)));
typedef __attribute__((ext_vector_type(4))) float f32x4;

__device__ __forceinline__ unsigned int pkh2(float a, float b){
  auto h = __builtin_amdgcn_cvt_pkrtz(a, b);
  return __builtin_bit_cast(unsigned int, h);
}
__device__ __forceinline__ half2v u2h(unsigned int u){
  return __builtin_bit_cast(half2v, u);
}
__device__ __forceinline__ unsigned int h2u(half2v v){
  return __builtin_bit_cast(unsigned int, v);
}
__device__ __forceinline__ unsigned int relu2(unsigned int d){
  half2v v = __builtin_elementwise_max(u2h(d), (half2v){(_Float16)0, (_Float16)0});
  return h2u(v);
}
__device__ __forceinline__ unsigned int bh1(unsigned int up, half2v c, unsigned int ap){
  half2v v = __builtin_elementwise_fma(u2h(up), c, u2h(ap));
  v = __builtin_elementwise_max(v, (half2v){(_Float16)0, (_Float16)0});
  return h2u(v);
}
__device__ __forceinline__ float dot4(float4 a, float4 b, float acc){
  acc = fmaf(a.x, b.x, acc); acc = fmaf(a.y, b.y, acc);
  acc = fmaf(a.z, b.z, acc); acc = fmaf(a.w, b.w, acc);
  return acc;
}

// ---------------- K1: prep (role-split: a1 | norms | fold) ----------------
__global__ __launch_bounds__(256) void k_prep(const float* t_, const float* s_,
    const float* W1, const float* W2, const float* W3, const float* Wc1,
    const float* g1, const float* b1, const float* m1, const float* v1,
    const float* g2, const float* b2, const float* m2, const float* v2,
    const float* g3, const float* b3, const float* m3, const float* v3,
    const float* gc1,const float* bc1,const float* mc1,const float* vc1,
    float* ws){
  __shared__ float W1s[64][133];
  int t = threadIdx.x;
  int bx = blockIdx.x;
  if (bx < 256){
    // ---- A1H[b][m][h] (f16) ----
    int b = bx >> 5, m0 = (bx & 31)*8;
    for (int idx = t; idx < 8192; idx += 256){
      int h = idx >> 7, f = idx & 127;
      W1s[h][f] = W1[h*129 + 1 + f];
    }
    __syncthreads();
    int h = t & 63, mg = t >> 6;
    const float* tp = t_ + (size_t)b*FF*MM + m0 + mg*2;
    float acc0 = 0.f, acc1 = 0.f;
    for (int f = 0; f < FF; f++){
      float wv = W1s[h][f];
      float2 tv = *(const float2*)&tp[(size_t)f*MM];
      acc0 = fmaf(wv, tv.x, acc0); acc1 = fmaf(wv, tv.y, acc1);
    }
    float a1 = g1[h] / sqrtf(v1[h] + BN_EPS);
    float c1 = b1[h] - a1*m1[h];
    unsigned short* dst = (unsigned short*)(ws + WS_A1) + ((size_t)(b*MM + m0 + mg*2))*64 + h;
    dst[0]  = (unsigned short)(pkh2(fmaf(a1, acc0, c1), 0.f) & 0xFFFFu);
    dst[64] = (unsigned short)(pkh2(fmaf(a1, acc1, c1), 0.f) & 0xFFFFu);
  } else if (bx < 416){
    // ---- norms ----
    __shared__ float red[4][64];
    int x = t & 63, fq = t >> 6;
    int idx = (bx - 256)*64 + x;
    const float* ptr; size_t stride;
    if (idx < BB*MM){
      int b = idx >> 8, m = idx & 255;
      ptr = t_ + (size_t)b*FF*MM + m; stride = MM;
    } else {
      int j = idx - BB*MM;
      int b = j >> 10, n = j & 1023;
      ptr = s_ + (size_t)b*FF*NN + n; stride = NN;
    }
    float acc = 0.f;
    for (int f = fq*32; f < fq*32 + 32; f++){
      float v = ptr[(size_t)f*stride]; acc = fmaf(v, v, acc);
    }
    red[fq][x] = acc;
    __syncthreads();
    if (fq == 0)
      ws[WS_NT + idx] = sqrtf(red[0][x] + red[1][x] + red[2][x] + red[3][x]);
  } else {
    // ---- fold ----
    if (t < 64){
      float a1 = g1[t] / sqrtf(v1[t] + BN_EPS);
      ws[WS_U + t]   = a1 * W1[t*129];
      float a2 = g2[t] / sqrtf(v2[t] + BN_EPS);
      ws[WS_C2 + t]  = b2[t] - a2*m2[t];
      float a3 = g3[t] / sqrtf(v3[t] + BN_EPS);
      ws[WS_C3 + t]  = b3[t] - a3*m3[t];
      float ac = gc1[t] / sqrtf(vc1[t] + BN_EPS);
      ws[WS_CC1 + t] = bc1[t] - ac*mc1[t];
    }
    unsigned short* w2h = (unsigned short*)(ws + WS_W2H);
    unsigned short* w3h = (unsigned short*)(ws + WS_W3H);
    for (int i = t; i < 4096; i += 256){
      int g = i >> 6;
      float a2 = g2[g] / sqrtf(v2[g] + BN_EPS);
      w2h[i] = __builtin_bit_cast(unsigned short, (_Float16)(a2 * W2[i]));
      float a3 = g3[g] / sqrtf(v3[g] + BN_EPS);
      w3h[i] = __builtin_bit_cast(unsigned short, (_Float16)(a3 * W3[i]));
      float ac = gc1[g] / sqrtf(vc1[g] + BN_EPS);
      ws[WS_WC1F + i] = ac * Wc1[i];
    }
  }
}

// ---------------- K2: cos via f16 MFMA. tile 64m x 64n ----------------
__global__ __launch_bounds__(256) void k_cos(const float* t_, const float* s_, float* ws){
  __shared__ __align__(16) unsigned short tS[64][136];
  __shared__ __align__(16) unsigned short sS[64][136];
  __shared__ float ntS[64], nsS[64];
  int t = threadIdx.x;
  int lane = t & 63, w = t >> 6;
  int ln15 = lane & 15, quad = lane >> 4;
  int m0 = blockIdx.x*64, n0 = blockIdx.y*64, b = blockIdx.z;
  {
    int x = t & 63;
    const float* tb = t_ + (size_t)b*FF*MM + m0 + x;
    const float* sb = s_ + (size_t)b*FF*NN + n0 + x;
    #pragma unroll
    for (int k = 0; k < 16; k++){
      int fp = w*16 + k;
      *(unsigned int*)&tS[x][2*fp] = pkh2(tb[(size_t)(2*fp)*MM], tb[(size_t)(2*fp+1)*MM]);
      *(unsigned int*)&sS[x][2*fp] = pkh2(sb[(size_t)(2*fp)*NN], sb[(size_t)(2*fp+1)*NN]);
    }
    if (t < 64) ntS[t] = ws[WS_NT + b*MM + m0 + t];
    else if (t < 128) nsS[t-64] = ws[WS_NS + b*NN + n0 + (t-64)];
  }
  __syncthreads();
  half8 A4[4];
  #pragma unroll
  for (int kc = 0; kc < 4; kc++)
    A4[kc] = *(const half8*)&tS[w*16 + ln15][kc*32 + quad*8];
  float4 nt4 = *(const float4*)&ntS[w*16 + quad*4];
  unsigned short* cosw = (unsigned short*)(ws + WS_COSH);
  #pragma unroll
  for (int ns = 0; ns < 4; ns++){
    f32x4 acc = (f32x4){0.f,0.f,0.f,0.f};
    #pragma unroll
    for (int kc = 0; kc < 4; kc++){
      half8 B4 = *(const half8*)&sS[ns*16 + ln15][kc*32 + quad*8];
      acc = __builtin_amdgcn_mfma_f32_16x16x32_f16(A4[kc], B4, acc, 0, 0, 0);
    }
    float nsv = nsS[ns*16 + ln15];
    int n = n0 + ns*16 + ln15;
    #pragma unroll
    for (int r = 0; r < 4; r++){
      int m = m0 + w*16 + quad*4 + r;
      float denom = fmaxf(nt4[r]*nsv, COS_EPS);
      float c = acc[r] * __builtin_amdgcn_rcpf(denom);
      cosw[(size_t)(b*MM + m)*NN + n] = (unsigned short)(pkh2(c, 0.f) & 0xFFFFu);
    }
  }
}

// ---------------- K3: main. grid (64,8,2), 4 waves; all waves share m, wave w owns g-slice [16w,16w+16) ----------------
__global__ __launch_bounds__(256, 4) void k_main(const float* ws, float* Pp){
  __shared__ __align__(16) unsigned short tile[2][16][72];  // h2 [n16][g64+pad], dbuf
  int t = threadIdx.x;
  int lane = t & 63, w = t >> 6;
  int ln15 = lane & 15, quad = lane >> 4;
  int b = blockIdx.y;
  int n0 = blockIdx.x * 16;
  int ms = blockIdx.z;

  // per-wave weight A-frags (prepacked f16 [g][k]), g-row = w*16 + ln15
  const unsigned short* w2h = (const unsigned short*)(ws + WS_W2H);
  const unsigned short* w3h = (const unsigned short*)(ws + WS_W3H);
  half8 W2A[2], W3A[2];
  #pragma unroll
  for (int kk = 0; kk < 2; kk++){
    W2A[kk] = *(const half8*)&w2h[(w*16 + ln15)*64 + kk*32 + quad*8];
    W3A[kk] = *(const half8*)&w3h[(w*16 + ln15)*64 + kk*32 + quad*8];
  }
  float4 cb2 = *(const float4*)&ws[WS_C2 + w*16 + quad*4];
  f32x4 c2v = (f32x4){cb2.x, cb2.y, cb2.z, cb2.w};
  f32x4 zf  = (f32x4){0.f, 0.f, 0.f, 0.f};

  // u[h] packed pairs for this lane's h-chunks (k = kk*32 + quad*8 + j)
  unsigned int upk[2][4];
  #pragma unroll
  for (int kk = 0; kk < 2; kk++){
    float4 ua = *(const float4*)&ws[WS_U + kk*32 + quad*8];
    float4 ub = *(const float4*)&ws[WS_U + kk*32 + quad*8 + 4];
    upk[kk][0] = pkh2(ua.x, ua.y); upk[kk][1] = pkh2(ua.z, ua.w);
    upk[kk][2] = pkh2(ub.x, ub.y); upk[kk][3] = pkh2(ub.z, ub.w);
  }
  const unsigned short* A1H = (const unsigned short*)(ws + WS_A1) + (size_t)b*MM*64;
  int n = n0 + ln15;                                // this lane's n (shared by all waves)
  const unsigned short* cosP = (const unsigned short*)(ws + WS_COSH)
                               + (size_t)b*MM*NN + n;

  f32x4 p = (f32x4){-3.0e38f, -3.0e38f, -3.0e38f, -3.0e38f};

  int m0i = ms*128;
  unsigned int cu = cosP[(size_t)m0i*NN];
  uint4 a1a = *(const uint4*)&A1H[(size_t)m0i*64 + quad*8];
  uint4 a1b = *(const uint4*)&A1H[(size_t)m0i*64 + 32 + quad*8];

  for (int mi = 0; mi < 128; mi++){
    // prefetch next m (overlaps with compute + barrier wait)
    int mN = ms*128 + (mi < 127 ? mi + 1 : 127);
    unsigned int cuN = cosP[(size_t)mN*NN];
    uint4 a1aN = *(const uint4*)&A1H[(size_t)mN*64 + quad*8];
    uint4 a1bN = *(const uint4*)&A1H[(size_t)mN*64 + 32 + quad*8];

    // build h1 B-frags in-register (same in all waves; k = kk*32+quad*8+j, n = ln15)
    unsigned int cd = cu | (cu << 16);
    half2v ch = u2h(cd);
    uint4 q0, q1;
    q0.x = bh1(upk[0][0], ch, a1a.x); q0.y = bh1(upk[0][1], ch, a1a.y);
    q0.z = bh1(upk[0][2], ch, a1a.z); q0.w = bh1(upk[0][3], ch, a1a.w);
    q1.x = bh1(upk[1][0], ch, a1b.x); q1.y = bh1(upk[1][1], ch, a1b.y);
    q1.z = bh1(upk[1][2], ch, a1b.z); q1.w = bh1(upk[1][3], ch, a1b.w);
    half8 b0h = __builtin_bit_cast(half8, q0);
    half8 b1h = __builtin_bit_cast(half8, q1);

    // layer 2: this wave's 16 g's
    f32x4 acc;
    acc = __builtin_amdgcn_mfma_f32_16x16x32_f16(W2A[0], b0h, c2v, 0, 0, 0);
    acc = __builtin_amdgcn_mfma_f32_16x16x32_f16(W2A[1], b1h, acc, 0, 0, 0);

    // relu + pack + transpose write: lane holds h2[g = w*16+quad*4+(0..3)][n=ln15]
    uint2 vv;
    vv.x = relu2(pkh2(acc[0], acc[1]));
    vv.y = relu2(pkh2(acc[2], acc[3]));
    *(uint2*)&tile[mi & 1][ln15][w*16 + quad*4] = vv;
    __syncthreads();

    // layer 3: B-frags from shared tile (k = g of h2)
    half8 e0 = *(const half8*)&tile[mi & 1][ln15][quad*8];
    half8 e1 = *(const half8*)&tile[mi & 1][ln15][32 + quad*8];
    f32x4 a3;
    a3 = __builtin_amdgcn_mfma_f32_16x16x32_f16(W3A[0], e0, zf, 0, 0, 0);
    a3 = __builtin_amdgcn_mfma_f32_16x16x32_f16(W3A[1], e1, a3, 0, 0, 0);
    #pragma unroll
    for (int r = 0; r < 4; r++) p[r] = fmaxf(p[r], a3[r]);

    cu = cuN; a1a = a1aN; a1b = a1bN;
  }

  // store: deferred c3 + relu; wave w owns g-slice [16w,16w+16) -> disjoint, no reduce
  float4 c3b = *(const float4*)&ws[WS_C3 + w*16 + quad*4];
  float* Pb = Pp + (size_t)ms*PS + ((size_t)(b*NN + n) << 6);
  float4 r4;
  r4.x = fmaxf(p[0] + c3b.x, 0.f);
  r4.y = fmaxf(p[1] + c3b.y, 0.f);
  r4.z = fmaxf(p[2] + c3b.z, 0.f);
  r4.w = fmaxf(p[3] + c3b.w, 0.f);
  *(float4*)&Pb[w*16 + quad*4] = r4;
}

// ---------------- K4: tail (max 2 partials, Wc1f/relu, Wc2+bias) fp32 ----------------
__global__ __launch_bounds__(256) void k_tail(const float* Wc2, const float* bc2,
                                              const float* ws, float* out){
  __shared__ float WT[64][68];
  __shared__ float pT[32][68];
  __shared__ float cS[32][68];
  int t = threadIdx.x;
  int n0 = blockIdx.x * 32;
  int b = blockIdx.y;
  for (int i = t; i < 4096; i += 256) WT[i >> 6][i & 63] = ws[WS_WC1F + i];
  const float* P0 = ws + WS_P + ((size_t)(b*NN + n0) << 6);
  const float* P1 = P0 + PS;
  for (int i = t; i < 2048; i += 256) pT[i >> 6][i & 63] = fmaxf(P0[i], P1[i]);
  __syncthreads();
  {
    int n = t & 31, q = t >> 5;
    for (int k = 0; k < 8; k++){
      int g = q*8 + k;
      float acc = ws[WS_CC1 + g];
      for (int hs = 0; hs < 64; hs += 4){
        float4 wv = *(const float4*)&WT[g][hs];
        float4 pv = *(const float4*)&pT[n][hs];
        acc = dot4(wv, pv, acc);
      }
      cS[n][g] = fmaxf(acc, 0.f);
    }
  }
  __syncthreads();
  {
    int o = t & 127, hf = t >> 7;
    float bco = bc2[o];
    float accO[16];
    #pragma unroll
    for (int i = 0; i < 16; i++) accO[i] = bco;
    for (int hs = 0; hs < 64; hs += 4){
      float4 w4 = *(const float4*)&Wc2[o*64 + hs];
      #pragma unroll
      for (int i = 0; i < 16; i++){
        float4 cv = *(const float4*)&cS[hf*16 + i][hs];
        accO[i] = dot4(w4, cv, accO[i]);
      }
    }
    #pragma unroll
    for (int i = 0; i < 16; i++)
      out[((size_t)(b*OO + o))*NN + n0 + hf*16 + i] = accO[i];
  }
}

extern "C" void kernel_launch(void* const* d_in, const int* in_sizes, int n_in,
                              void* d_out, int out_size, void* d_ws, size_t ws_size,
                              hipStream_t stream){
  (void)in_sizes; (void)n_in; (void)out_size; (void)ws_size;
  const float* t_  = (const float*)d_in[0];
  const float* s_  = (const float*)d_in[1];
  const float* W1  = (const float*)d_in[2];
  const float* W2  = (const float*)d_in[3];
  const float* W3  = (const float*)d_in[4];
  const float* Wc1 = (const float*)d_in[5];
  const float* Wc2 = (const float*)d_in[6];
  const float* bc2 = (const float*)d_in[7];
  const float* g1 = (const float*)d_in[8],  *b1 = (const float*)d_in[9],
             * m1 = (const float*)d_in[10], *v1 = (const float*)d_in[11];
  const float* g2 = (const float*)d_in[12], *b2 = (const float*)d_in[13],
             * m2 = (const float*)d_in[14], *v2 = (const float*)d_in[15];
  const float* g3 = (const float*)d_in[16], *b3 = (const float*)d_in[17],
             * m3 = (const float*)d_in[18], *v3 = (const float*)d_in[19];
  const float* gc1 = (const float*)d_in[20], *bc1 = (const float*)d_in[21],
             * mc1 = (const float*)d_in[22], *vc1 = (const float*)d_in[23];
  float* ws = (float*)d_ws;
  float* out = (float*)d_out;

  k_prep<<<417, 256, 0, stream>>>(t_, s_, W1, W2, W3, Wc1,
      g1,b1,m1,v1, g2,b2,m2,v2, g3,b3,m3,v3, gc1,bc1,mc1,vc1, ws);
  k_cos<<<dim3(4, 16, 8), 256, 0, stream>>>(t_, s_, ws);
  k_main<<<dim3(64, 8, 2), 256, 0, stream>>>(ws, ws + WS_P);
  k_tail<<<dim3(32, 8), 256, 0, stream>>>(Wc2, bc2, ws, out);
}

// Round 3
// 189.462 us; speedup vs baseline: 1.4097x; 1.0497x over previous
//
#include <hip/hip_runtime.h>

// P2B_XCorr: B=8, F=128, M=256, N=1024, H=64, O=128. fp32 I/O.
// R11 = R8's k_main interior (proven 57us: m-parity x n-half wave split, 1x h1
//   build, 16 MFMA/iter, per-wave LDS tile, NO in-loop barriers, 84 VGPR at
//   (256,3)) with the grid grown to exactly 3 blocks/CU:
//   - M split 3 ways (86/85/85): grid (32,8,3) = 768 blocks, zero tail.
//     (R9 proved this live set spills at the 128-reg cap of (256,4); 3
//     waves/EU cap=168 is the max safe occupancy for the 4-rt layout.)
//   - P collapsed to ONE slice via atomicMax on uint bit patterns: stored
//     values are max(0,h3) >= 0 (p seeded 0), and non-negative IEEE floats
//     are uint-monotone -> integer atomicMax is exact and order-independent.
//     k_prep zeroes P (blocks 417..480). No cross-wave combine epilogue.
//   - weights from R10's f16 prepack (A-frag-ready b128 loads).
//   - k_tail reads single P slice.
// R10 post-mortem: g-split duplicated h1 build 4x -> VALU-time 23.4->43.8us
//   (MFMA-time conserved 13.5 vs 14.2us) -> 79us. Occupancy gains cancel if
//   the restructure multiplies work on the binding pipe.
// Frag layouts (HW-verified): A[m=lane&15][k=quad*8+j], B[k=quad*8+j][n=lane&15],
// D[row=quad*4+reg][col=lane&15].

#define BB 8
#define FF 128
#define MM 256
#define NN 1024
#define HH 64
#define OO 128
#define BN_EPS 1e-5f
#define COS_EPS 1e-8f

// ws layout (float offsets); total 2,251,008 floats = 8.59 MiB (proven envelope)
#define WS_U     0
#define WS_C2    64
#define WS_C3    128
#define WS_CC1   192
#define WS_W2H   256          // f16 [64][64] folded a2*W2 (2048 float slots)
#define WS_W3H   2304         // f16 [64][64] folded a3*W3 (2048 float slots)
#define WS_WC1F  8448
#define WS_A1    12544        // f16 A1H[b][m][64]
#define WS_NT    143616       // [b][m] fp32 (NS contiguous after)
#define WS_NS    145664       // [b][n] fp32
#define WS_COSH  153856       // f16 cos[b][m][n]
#define WS_P     1202432      // fp32 single slice [b][n][64], atomicMax-combined

typedef _Float16 half2v __attribute__((ext_vector_type(2)));
typedef _Float16 half8  __attribute__((ext_vector_type(8)));
typedef __attribute__((ext_vector_type(4))) float f32x4;

__device__ __forceinline__ unsigned int pkh2(float a, float b){
  auto h = __builtin_amdgcn_cvt_pkrtz(a, b);
  return __builtin_bit_cast(unsigned int, h);
}
__device__ __forceinline__ half2v u2h(unsigned int u){
  return __builtin_bit_cast(half2v, u);
}
__device__ __forceinline__ unsigned int h2u(half2v v){
  return __builtin_bit_cast(unsigned int, v);
}
__device__ __forceinline__ unsigned int relu2(unsigned int d){
  half2v v = __builtin_elementwise_max(u2h(d), (half2v){(_Float16)0, (_Float16)0});
  return h2u(v);
}
__device__ __forceinline__ unsigned int bh1(unsigned int up, half2v c, unsigned int ap){
  half2v v = __builtin_elementwise_fma(u2h(up), c, u2h(ap));
  v = __builtin_elementwise_max(v, (half2v){(_Float16)0, (_Float16)0});
  return h2u(v);
}
__device__ __forceinline__ float dot4(float4 a, float4 b, float acc){
  acc = fmaf(a.x, b.x, acc); acc = fmaf(a.y, b.y, acc);
  acc = fmaf(a.z, b.z, acc); acc = fmaf(a.w, b.w, acc);
  return acc;
}

// ---------------- K1: prep (role-split: a1 | norms | fold | zero-P) ----------------
__global__ __launch_bounds__(256) void k_prep(const float* t_, const float* s_,
    const float* W1, const float* W2, const float* W3, const float* Wc1,
    const float* g1, const float* b1, const float* m1, const float* v1,
    const float* g2, const float* b2, const float* m2, const float* v2,
    const float* g3, const float* b3, const float* m3, const float* v3,
    const float* gc1,const float* bc1,const float* mc1,const float* vc1,
    float* ws){
  __shared__ float W1s[64][133];
  int t = threadIdx.x;
  int bx = blockIdx.x;
  if (bx < 256){
    // ---- A1H[b][m][h] (f16) ----
    int b = bx >> 5, m0 = (bx & 31)*8;
    for (int idx = t; idx < 8192; idx += 256){
      int h = idx >> 7, f = idx & 127;
      W1s[h][f] = W1[h*129 + 1 + f];
    }
    __syncthreads();
    int h = t & 63, mg = t >> 6;
    const float* tp = t_ + (size_t)b*FF*MM + m0 + mg*2;
    float acc0 = 0.f, acc1 = 0.f;
    for (int f = 0; f < FF; f++){
      float wv = W1s[h][f];
      float2 tv = *(const float2*)&tp[(size_t)f*MM];
      acc0 = fmaf(wv, tv.x, acc0); acc1 = fmaf(wv, tv.y, acc1);
    }
    float a1 = g1[h] / sqrtf(v1[h] + BN_EPS);
    float c1 = b1[h] - a1*m1[h];
    unsigned short* dst = (unsigned short*)(ws + WS_A1) + ((size_t)(b*MM + m0 + mg*2))*64 + h;
    dst[0]  = (unsigned short)(pkh2(fmaf(a1, acc0, c1), 0.f) & 0xFFFFu);
    dst[64] = (unsigned short)(pkh2(fmaf(a1, acc1, c1), 0.f) & 0xFFFFu);
  } else if (bx < 416){
    // ---- norms ----
    __shared__ float red[4][64];
    int x = t & 63, fq = t >> 6;
    int idx = (bx - 256)*64 + x;
    const float* ptr; size_t stride;
    if (idx < BB*MM){
      int b = idx >> 8, m = idx & 255;
      ptr = t_ + (size_t)b*FF*MM + m; stride = MM;
    } else {
      int j = idx - BB*MM;
      int b = j >> 10, n = j & 1023;
      ptr = s_ + (size_t)b*FF*NN + n; stride = NN;
    }
    float acc = 0.f;
    for (int f = fq*32; f < fq*32 + 32; f++){
      float v = ptr[(size_t)f*stride]; acc = fmaf(v, v, acc);
    }
    red[fq][x] = acc;
    __syncthreads();
    if (fq == 0)
      ws[WS_NT + idx] = sqrtf(red[0][x] + red[1][x] + red[2][x] + red[3][x]);
  } else if (bx == 416){
    // ---- fold ----
    if (t < 64){
      float a1 = g1[t] / sqrtf(v1[t] + BN_EPS);
      ws[WS_U + t]   = a1 * W1[t*129];
      float a2 = g2[t] / sqrtf(v2[t] + BN_EPS);
      ws[WS_C2 + t]  = b2[t] - a2*m2[t];
      float a3 = g3[t] / sqrtf(v3[t] + BN_EPS);
      ws[WS_C3 + t]  = b3[t] - a3*m3[t];
      float ac = gc1[t] / sqrtf(vc1[t] + BN_EPS);
      ws[WS_CC1 + t] = bc1[t] - ac*mc1[t];
    }
    unsigned short* w2h = (unsigned short*)(ws + WS_W2H);
    unsigned short* w3h = (unsigned short*)(ws + WS_W3H);
    for (int i = t; i < 4096; i += 256){
      int g = i >> 6;
      float a2 = g2[g] / sqrtf(v2[g] + BN_EPS);
      w2h[i] = __builtin_bit_cast(unsigned short, (_Float16)(a2 * W2[i]));
      float a3 = g3[g] / sqrtf(v3[g] + BN_EPS);
      w3h[i] = __builtin_bit_cast(unsigned short, (_Float16)(a3 * W3[i]));
      float ac = gc1[g] / sqrtf(vc1[g] + BN_EPS);
      ws[WS_WC1F + i] = ac * Wc1[i];
    }
  } else {
    // ---- zero P (blocks 417..480; 64 blocks x 8192 floats = 524288) ----
    float4 z4 = make_float4(0.f, 0.f, 0.f, 0.f);
    size_t base = (size_t)WS_P + (size_t)(bx - 417)*8192;
    for (int i = t; i < 2048; i += 256)
      *(float4*)&ws[base + (size_t)i*4] = z4;
  }
}

// ---------------- K2: cos via f16 MFMA. tile 64m x 64n ----------------
__global__ __launch_bounds__(256) void k_cos(const float* t_, const float* s_, float* ws){
  __shared__ __align__(16) unsigned short tS[64][136];
  __shared__ __align__(16) unsigned short sS[64][136];
  __shared__ float ntS[64], nsS[64];
  int t = threadIdx.x;
  int lane = t & 63, w = t >> 6;
  int ln15 = lane & 15, quad = lane >> 4;
  int m0 = blockIdx.x*64, n0 = blockIdx.y*64, b = blockIdx.z;
  {
    int x = t & 63;
    const float* tb = t_ + (size_t)b*FF*MM + m0 + x;
    const float* sb = s_ + (size_t)b*FF*NN + n0 + x;
    #pragma unroll
    for (int k = 0; k < 16; k++){
      int fp = w*16 + k;
      *(unsigned int*)&tS[x][2*fp] = pkh2(tb[(size_t)(2*fp)*MM], tb[(size_t)(2*fp+1)*MM]);
      *(unsigned int*)&sS[x][2*fp] = pkh2(sb[(size_t)(2*fp)*NN], sb[(size_t)(2*fp+1)*NN]);
    }
    if (t < 64) ntS[t] = ws[WS_NT + b*MM + m0 + t];
    else if (t < 128) nsS[t-64] = ws[WS_NS + b*NN + n0 + (t-64)];
  }
  __syncthreads();
  half8 A4[4];
  #pragma unroll
  for (int kc = 0; kc < 4; kc++)
    A4[kc] = *(const half8*)&tS[w*16 + ln15][kc*32 + quad*8];
  float4 nt4 = *(const float4*)&ntS[w*16 + quad*4];
  unsigned short* cosw = (unsigned short*)(ws + WS_COSH);
  #pragma unroll
  for (int ns = 0; ns < 4; ns++){
    f32x4 acc = (f32x4){0.f,0.f,0.f,0.f};
    #pragma unroll
    for (int kc = 0; kc < 4; kc++){
      half8 B4 = *(const half8*)&sS[ns*16 + ln15][kc*32 + quad*8];
      acc = __builtin_amdgcn_mfma_f32_16x16x32_f16(A4[kc], B4, acc, 0, 0, 0);
    }
    float nsv = nsS[ns*16 + ln15];
    int n = n0 + ns*16 + ln15;
    #pragma unroll
    for (int r = 0; r < 4; r++){
      int m = m0 + w*16 + quad*4 + r;
      float denom = fmaxf(nt4[r]*nsv, COS_EPS);
      float c = acc[r] * __builtin_amdgcn_rcpf(denom);
      cosw[(size_t)(b*MM + m)*NN + n] = (unsigned short)(pkh2(c, 0.f) & 0xFFFFu);
    }
  }
}

// ---------------- K3: main. grid (32,8,3), 4 waves; wave w: m-parity w>>1, n-half w&1 ----------------
__global__ __launch_bounds__(256, 3) void k_main(const float* ws, float* Pp){
  __shared__ __align__(16) unsigned short h2W[4][16][72];  // per-wave [x16][g64+pad]
  int t = threadIdx.x;
  int lane = t & 63, w = t >> 6;
  int ln15 = lane & 15, quad = lane >> 4;
  int b = blockIdx.y;
  int n0 = blockIdx.x * 32;
  int ms = blockIdx.z;
  int mstart = (ms == 0) ? 0 : (ms == 1 ? 86 : 171);
  int mlen   = (ms == 0) ? 86 : 85;

  // weight A-frags (prepacked f16 [g][k]) + bias C-vectors
  const unsigned short* w2h = (const unsigned short*)(ws + WS_W2H);
  const unsigned short* w3h = (const unsigned short*)(ws + WS_W3H);
  half8 W2A[4][2], W3A[4][2];
  f32x4 c2v[4], c3v[4];
  #pragma unroll
  for (int rt = 0; rt < 4; rt++){
    int g = rt*16 + ln15;
    #pragma unroll
    for (int kk = 0; kk < 2; kk++){
      W2A[rt][kk] = *(const half8*)&w2h[g*64 + kk*32 + quad*8];
      W3A[rt][kk] = *(const half8*)&w3h[g*64 + kk*32 + quad*8];
    }
    float4 cb2 = *(const float4*)&ws[WS_C2 + rt*16 + quad*4];
    float4 cb3 = *(const float4*)&ws[WS_C3 + rt*16 + quad*4];
    c2v[rt] = (f32x4){cb2.x, cb2.y, cb2.z, cb2.w};
    c3v[rt] = (f32x4){cb3.x, cb3.y, cb3.z, cb3.w};
  }
  // u[h] packed pairs for this lane's h-chunks
  unsigned int upk[2][4];
  #pragma unroll
  for (int kk = 0; kk < 2; kk++){
    float4 ua = *(const float4*)&ws[WS_U + kk*32 + quad*8];
    float4 ub = *(const float4*)&ws[WS_U + kk*32 + quad*8 + 4];
    upk[kk][0] = pkh2(ua.x, ua.y); upk[kk][1] = pkh2(ua.z, ua.w);
    upk[kk][2] = pkh2(ub.x, ub.y); upk[kk][3] = pkh2(ub.z, ub.w);
  }
  const unsigned short* A1H = (const unsigned short*)(ws + WS_A1) + (size_t)b*MM*64;
  int mp = w >> 1;                                  // m-parity handled by this wave
  int n  = n0 + (w & 1)*16 + ln15;                  // this lane's x/n
  const unsigned short* cosP = (const unsigned short*)(ws + WS_COSH)
                               + (size_t)b*MM*NN + n;
  unsigned short* h2w = &h2W[w][0][0];

  f32x4 p[4];
  #pragma unroll
  for (int rt = 0; rt < 4; rt++) p[rt] = (f32x4){0.f,0.f,0.f,0.f};

  int mcnt = (mlen - mp + 1) >> 1;                  // iterations for this parity
  int m0i = mstart + mp;
  unsigned int cu = cosP[(size_t)m0i*NN];
  uint4 a1a = *(const uint4*)&A1H[(size_t)m0i*64 + quad*8];
  uint4 a1b = *(const uint4*)&A1H[(size_t)m0i*64 + 32 + quad*8];

  for (int mc = 0; mc < mcnt; mc++){
    // prefetch next mc
    int mN = mstart + (mc < mcnt-1 ? (mc + 1) : (mcnt-1))*2 + mp;
    unsigned int cuN = cosP[(size_t)mN*NN];
    uint4 a1aN = *(const uint4*)&A1H[(size_t)mN*64 + quad*8];
    uint4 a1bN = *(const uint4*)&A1H[(size_t)mN*64 + 32 + quad*8];

    unsigned int cd = cu | (cu << 16);
    half2v ch = u2h(cd);
    uint4 q0, q1;
    q0.x = bh1(upk[0][0], ch, a1a.x); q0.y = bh1(upk[0][1], ch, a1a.y);
    q0.z = bh1(upk[0][2], ch, a1a.z); q0.w = bh1(upk[0][3], ch, a1a.w);
    q1.x = bh1(upk[1][0], ch, a1b.x); q1.y = bh1(upk[1][1], ch, a1b.y);
    q1.z = bh1(upk[1][2], ch, a1b.z); q1.w = bh1(upk[1][3], ch, a1b.w);
    half8 b0h = __builtin_bit_cast(half8, q0);
    half8 b1h = __builtin_bit_cast(half8, q1);

    // layer 2
    f32x4 acc[4];
    #pragma unroll
    for (int rt = 0; rt < 4; rt++){
      acc[rt] = __builtin_amdgcn_mfma_f32_16x16x32_f16(W2A[rt][0], b0h, c2v[rt], 0, 0, 0);
      acc[rt] = __builtin_amdgcn_mfma_f32_16x16x32_f16(W2A[rt][1], b1h, acc[rt], 0, 0, 0);
    }
    // relu + pack + h2 transpose write (g = rt*16 + quad*4 + r, row x = ln15)
    #pragma unroll
    for (int rt = 0; rt < 4; rt++){
      uint2 vv;
      vv.x = relu2(pkh2(acc[rt][0], acc[rt][1]));
      vv.y = relu2(pkh2(acc[rt][2], acc[rt][3]));
      *(uint2*)&h2w[ln15*72 + rt*16 + quad*4] = vv;
    }
    __asm__ volatile("s_waitcnt lgkmcnt(0)" ::: "memory");
    half8 e0 = *(const half8*)&h2w[ln15*72 + quad*8];
    half8 e1 = *(const half8*)&h2w[ln15*72 + 32 + quad*8];
    // layer 3 + running max (p seeded 0 => stored value = max(0, h3) exactly)
    #pragma unroll
    for (int rt = 0; rt < 4; rt++){
      f32x4 a3 = __builtin_amdgcn_mfma_f32_16x16x32_f16(W3A[rt][0], e0, c3v[rt], 0, 0, 0);
      a3 = __builtin_amdgcn_mfma_f32_16x16x32_f16(W3A[rt][1], e1, a3, 0, 0, 0);
      #pragma unroll
      for (int r = 0; r < 4; r++) p[rt][r] = fmaxf(p[rt][r], a3[r]);
    }
    cu = cuN; a1a = a1aN; a1b = a1bN;
  }

  // epilogue: device-scope atomicMax on uint bit patterns. Values >= 0 (p
  // seeded 0), non-negative IEEE floats are uint-monotone -> exact max.
  unsigned int* Pb = (unsigned int*)(Pp + ((size_t)(b*NN + n) << 6));
  #pragma unroll
  for (int rt = 0; rt < 4; rt++){
    #pragma unroll
    for (int r = 0; r < 4; r++)
      atomicMax(&Pb[rt*16 + quad*4 + r], __float_as_uint(p[rt][r]));
  }
}

// ---------------- K4: tail (single P slice, Wc1f/relu, Wc2+bias) fp32 ----------------
__global__ __launch_bounds__(256) void k_tail(const float* Wc2, const float* bc2,
                                              const float* ws, float* out){
  __shared__ float WT[64][68];
  __shared__ float pT[32][68];
  __shared__ float cS[32][68];
  int t = threadIdx.x;
  int n0 = blockIdx.x * 32;
  int b = blockIdx.y;
  for (int i = t; i < 4096; i += 256) WT[i >> 6][i & 63] = ws[WS_WC1F + i];
  const float* P0 = ws + WS_P + ((size_t)(b*NN + n0) << 6);
  for (int i = t; i < 2048; i += 256) pT[i >> 6][i & 63] = P0[i];
  __syncthreads();
  {
    int n = t & 31, q = t >> 5;
    for (int k = 0; k < 8; k++){
      int g = q*8 + k;
      float acc = ws[WS_CC1 + g];
      for (int hs = 0; hs < 64; hs += 4){
        float4 wv = *(const float4*)&WT[g][hs];
        float4 pv = *(const float4*)&pT[n][hs];
        acc = dot4(wv, pv, acc);
      }
      cS[n][g] = fmaxf(acc, 0.f);
    }
  }
  __syncthreads();
  {
    int o = t & 127, hf = t >> 7;
    float bco = bc2[o];
    float accO[16];
    #pragma unroll
    for (int i = 0; i < 16; i++) accO[i] = bco;
    for (int hs = 0; hs < 64; hs += 4){
      float4 w4 = *(const float4*)&Wc2[o*64 + hs];
      #pragma unroll
      for (int i = 0; i < 16; i++){
        float4 cv = *(const float4*)&cS[hf*16 + i][hs];
        accO[i] = dot4(w4, cv, accO[i]);
      }
    }
    #pragma unroll
    for (int i = 0; i < 16; i++)
      out[((size_t)(b*OO + o))*NN + n0 + hf*16 + i] = accO[i];
  }
}

extern "C" void kernel_launch(void* const* d_in, const int* in_sizes, int n_in,
                              void* d_out, int out_size, void* d_ws, size_t ws_size,
                              hipStream_t stream){
  (void)in_sizes; (void)n_in; (void)out_size; (void)ws_size;
  const float* t_  = (const float*)d_in[0];
  const float* s_  = (const float*)d_in[1];
  const float* W1  = (const float*)d_in[2];
  const float* W2  = (const float*)d_in[3];
  const float* W3  = (const float*)d_in[4];
  const float* Wc1 = (const float*)d_in[5];
  const float* Wc2 = (const float*)d_in[6];
  const float* bc2 = (const float*)d_in[7];
  const float* g1 = (const float*)d_in[8],  *b1 = (const float*)d_in[9],
             * m1 = (const float*)d_in[10], *v1 = (const float*)d_in[11];
  const float* g2 = (const float*)d_in[12], *b2 = (const float*)d_in[13],
             * m2 = (const float*)d_in[14], *v2 = (const float*)d_in[15];
  const float* g3 = (const float*)d_in[16], *b3 = (const float*)d_in[17],
             * m3 = (const float*)d_in[18], *v3 = (const float*)d_in[19];
  const float* gc1 = (const float*)d_in[20], *bc1 = (const float*)d_in[21],
             * mc1 = (const float*)d_in[22], *vc1 = (const float*)d_in[23];
  float* ws = (float*)d_ws;
  float* out = (float*)d_out;

  k_prep<<<481, 256, 0, stream>>>(t_, s_, W1, W2, W3, Wc1,
      g1,b1,m1,v1, g2,b2,m2,v2, g3,b3,m3,v3, gc1,bc1,mc1,vc1, ws);
  k_cos<<<dim3(4, 16, 8), 256, 0, stream>>>(t_, s_, ws);
  k_main<<<dim3(32, 8, 3), 256, 0, stream>>>(ws, ws + WS_P);
  k_tail<<<dim3(32, 8), 256, 0, stream>>>(Wc2, bc2, ws, out);
}

// Round 4
// 183.186 us; speedup vs baseline: 1.4580x; 1.0343x over previous
//
#include <hip/hip_runtime.h>

// P2B_XCorr: B=8, F=128, M=256, N=1024, H=64, O=128. fp32 I/O.
// R12 = R9's k_main structure at the spill-safe bound (the one-line fix R9
//   needed): grid (64,8,2) = 1024 blocks, 16 n-cols/block, 4 waves with
//   m = ms*128 + mc*4 + w (mc 0..31), in-block 4-way LDS max combine,
//   plain stores to 2 P slices. __launch_bounds__(256,3): R9 proved this
//   live set (~84 VGPR + ~64 AGPR) spills at the 128-reg (256,4) cap;
//   (256,3) holds it spill-free (R8/R11 evidence) at 3 blocks/CU.
// R11 post-mortem: global atomicMax epilogue cost more than occupancy gained
//   (WRITE 7->49 MB, serialized RMW tail, VALUBusy 41->32). Reductions stay
//   in-block; P back to 2 slices + k_tail max.
// Frag layouts (HW-verified): A[m=lane&15][k=quad*8+j], B[k=quad*8+j][n=lane&15],
// D[row=quad*4+reg][col=lane&15].

#define BB 8
#define FF 128
#define MM 256
#define NN 1024
#define HH 64
#define OO 128
#define BN_EPS 1e-5f
#define COS_EPS 1e-8f

// ws layout (float offsets); total 2,251,008 floats = 8.59 MiB (proven envelope)
#define WS_U     0
#define WS_C2    64
#define WS_C3    128
#define WS_CC1   192
#define WS_W2H   256          // f16 [64][64] folded a2*W2 (2048 float slots)
#define WS_W3H   2304         // f16 [64][64] folded a3*W3 (2048 float slots)
#define WS_WC1F  8448
#define WS_A1    12544        // f16 A1H[b][m][64]
#define WS_NT    143616       // [b][m] fp32 (NS contiguous after)
#define WS_NS    145664       // [b][n] fp32
#define WS_COSH  153856       // f16 cos[b][m][n]
#define WS_P     1202432      // fp32 partials [2][b][n][64]
#define PS       524288

typedef _Float16 half2v __attribute__((ext_vector_type(2)));
typedef _Float16 half8  __attribute__((ext_vector_type(8)));
typedef __attribute__((ext_vector_type(4))) float f32x4;

__device__ __forceinline__ unsigned int pkh2(float a, float b){
  auto h = __builtin_amdgcn_cvt_pkrtz(a, b);
  return __builtin_bit_cast(unsigned int, h);
}
__device__ __forceinline__ half2v u2h(unsigned int u){
  return __builtin_bit_cast(half2v, u);
}
__device__ __forceinline__ unsigned int h2u(half2v v){
  return __builtin_bit_cast(unsigned int, v);
}
__device__ __forceinline__ unsigned int relu2(unsigned int d){
  half2v v = __builtin_elementwise_max(u2h(d), (half2v){(_Float16)0, (_Float16)0});
  return h2u(v);
}
__device__ __forceinline__ unsigned int bh1(unsigned int up, half2v c, unsigned int ap){
  half2v v = __builtin_elementwise_fma(u2h(up), c, u2h(ap));
  v = __builtin_elementwise_max(v, (half2v){(_Float16)0, (_Float16)0});
  return h2u(v);
}
__device__ __forceinline__ float dot4(float4 a, float4 b, float acc){
  acc = fmaf(a.x, b.x, acc); acc = fmaf(a.y, b.y, acc);
  acc = fmaf(a.z, b.z, acc); acc = fmaf(a.w, b.w, acc);
  return acc;
}

// ---------------- K1: prep (role-split: a1 | norms | fold) ----------------
__global__ __launch_bounds__(256) void k_prep(const float* t_, const float* s_,
    const float* W1, const float* W2, const float* W3, const float* Wc1,
    const float* g1, const float* b1, const float* m1, const float* v1,
    const float* g2, const float* b2, const float* m2, const float* v2,
    const float* g3, const float* b3, const float* m3, const float* v3,
    const float* gc1,const float* bc1,const float* mc1,const float* vc1,
    float* ws){
  __shared__ float W1s[64][133];
  int t = threadIdx.x;
  int bx = blockIdx.x;
  if (bx < 256){
    // ---- A1H[b][m][h] (f16) ----
    int b = bx >> 5, m0 = (bx & 31)*8;
    for (int idx = t; idx < 8192; idx += 256){
      int h = idx >> 7, f = idx & 127;
      W1s[h][f] = W1[h*129 + 1 + f];
    }
    __syncthreads();
    int h = t & 63, mg = t >> 6;
    const float* tp = t_ + (size_t)b*FF*MM + m0 + mg*2;
    float acc0 = 0.f, acc1 = 0.f;
    for (int f = 0; f < FF; f++){
      float wv = W1s[h][f];
      float2 tv = *(const float2*)&tp[(size_t)f*MM];
      acc0 = fmaf(wv, tv.x, acc0); acc1 = fmaf(wv, tv.y, acc1);
    }
    float a1 = g1[h] / sqrtf(v1[h] + BN_EPS);
    float c1 = b1[h] - a1*m1[h];
    unsigned short* dst = (unsigned short*)(ws + WS_A1) + ((size_t)(b*MM + m0 + mg*2))*64 + h;
    dst[0]  = (unsigned short)(pkh2(fmaf(a1, acc0, c1), 0.f) & 0xFFFFu);
    dst[64] = (unsigned short)(pkh2(fmaf(a1, acc1, c1), 0.f) & 0xFFFFu);
  } else if (bx < 416){
    // ---- norms ----
    __shared__ float red[4][64];
    int x = t & 63, fq = t >> 6;
    int idx = (bx - 256)*64 + x;
    const float* ptr; size_t stride;
    if (idx < BB*MM){
      int b = idx >> 8, m = idx & 255;
      ptr = t_ + (size_t)b*FF*MM + m; stride = MM;
    } else {
      int j = idx - BB*MM;
      int b = j >> 10, n = j & 1023;
      ptr = s_ + (size_t)b*FF*NN + n; stride = NN;
    }
    float acc = 0.f;
    for (int f = fq*32; f < fq*32 + 32; f++){
      float v = ptr[(size_t)f*stride]; acc = fmaf(v, v, acc);
    }
    red[fq][x] = acc;
    __syncthreads();
    if (fq == 0)
      ws[WS_NT + idx] = sqrtf(red[0][x] + red[1][x] + red[2][x] + red[3][x]);
  } else {
    // ---- fold ----
    if (t < 64){
      float a1 = g1[t] / sqrtf(v1[t] + BN_EPS);
      ws[WS_U + t]   = a1 * W1[t*129];
      float a2 = g2[t] / sqrtf(v2[t] + BN_EPS);
      ws[WS_C2 + t]  = b2[t] - a2*m2[t];
      float a3 = g3[t] / sqrtf(v3[t] + BN_EPS);
      ws[WS_C3 + t]  = b3[t] - a3*m3[t];
      float ac = gc1[t] / sqrtf(vc1[t] + BN_EPS);
      ws[WS_CC1 + t] = bc1[t] - ac*mc1[t];
    }
    unsigned short* w2h = (unsigned short*)(ws + WS_W2H);
    unsigned short* w3h = (unsigned short*)(ws + WS_W3H);
    for (int i = t; i < 4096; i += 256){
      int g = i >> 6;
      float a2 = g2[g] / sqrtf(v2[g] + BN_EPS);
      w2h[i] = __builtin_bit_cast(unsigned short, (_Float16)(a2 * W2[i]));
      float a3 = g3[g] / sqrtf(v3[g] + BN_EPS);
      w3h[i] = __builtin_bit_cast(unsigned short, (_Float16)(a3 * W3[i]));
      float ac = gc1[g] / sqrtf(vc1[g] + BN_EPS);
      ws[WS_WC1F + i] = ac * Wc1[i];
    }
  }
}

// ---------------- K2: cos via f16 MFMA. tile 64m x 64n ----------------
__global__ __launch_bounds__(256) void k_cos(const float* t_, const float* s_, float* ws){
  __shared__ __align__(16) unsigned short tS[64][136];
  __shared__ __align__(16) unsigned short sS[64][136];
  __shared__ float ntS[64], nsS[64];
  int t = threadIdx.x;
  int lane = t & 63, w = t >> 6;
  int ln15 = lane & 15, quad = lane >> 4;
  int m0 = blockIdx.x*64, n0 = blockIdx.y*64, b = blockIdx.z;
  {
    int x = t & 63;
    const float* tb = t_ + (size_t)b*FF*MM + m0 + x;
    const float* sb = s_ + (size_t)b*FF*NN + n0 + x;
    #pragma unroll
    for (int k = 0; k < 16; k++){
      int fp = w*16 + k;
      *(unsigned int*)&tS[x][2*fp] = pkh2(tb[(size_t)(2*fp)*MM], tb[(size_t)(2*fp+1)*MM]);
      *(unsigned int*)&sS[x][2*fp] = pkh2(sb[(size_t)(2*fp)*NN], sb[(size_t)(2*fp+1)*NN]);
    }
    if (t < 64) ntS[t] = ws[WS_NT + b*MM + m0 + t];
    else if (t < 128) nsS[t-64] = ws[WS_NS + b*NN + n0 + (t-64)];
  }
  __syncthreads();
  half8 A4[4];
  #pragma unroll
  for (int kc = 0; kc < 4; kc++)
    A4[kc] = *(const half8*)&tS[w*16 + ln15][kc*32 + quad*8];
  float4 nt4 = *(const float4*)&ntS[w*16 + quad*4];
  unsigned short* cosw = (unsigned short*)(ws + WS_COSH);
  #pragma unroll
  for (int ns = 0; ns < 4; ns++){
    f32x4 acc = (f32x4){0.f,0.f,0.f,0.f};
    #pragma unroll
    for (int kc = 0; kc < 4; kc++){
      half8 B4 = *(const half8*)&sS[ns*16 + ln15][kc*32 + quad*8];
      acc = __builtin_amdgcn_mfma_f32_16x16x32_f16(A4[kc], B4, acc, 0, 0, 0);
    }
    float nsv = nsS[ns*16 + ln15];
    int n = n0 + ns*16 + ln15;
    #pragma unroll
    for (int r = 0; r < 4; r++){
      int m = m0 + w*16 + quad*4 + r;
      float denom = fmaxf(nt4[r]*nsv, COS_EPS);
      float c = acc[r] * __builtin_amdgcn_rcpf(denom);
      cosw[(size_t)(b*MM + m)*NN + n] = (unsigned short)(pkh2(c, 0.f) & 0xFFFFu);
    }
  }
}

// ---------------- K3: main. grid (64,8,2), 4 waves; wave w: m = ms*128 + mc*4 + w ----------------
__global__ __launch_bounds__(256, 3) void k_main(const float* ws, float* Pp){
  __shared__ __align__(16) unsigned short h2W[4][16][72];  // per-wave [x16][g64+pad]
  __shared__ __align__(16) float redS[3][16][68];          // parked partials (waves 1..3)
  int t = threadIdx.x;
  int lane = t & 63, w = t >> 6;
  int ln15 = lane & 15, quad = lane >> 4;
  int b = blockIdx.y;
  int n0 = blockIdx.x * 16;
  int ms = blockIdx.z;

  // weight A-frags (prepacked f16 [g][k]) + bias C-vectors
  const unsigned short* w2h = (const unsigned short*)(ws + WS_W2H);
  const unsigned short* w3h = (const unsigned short*)(ws + WS_W3H);
  half8 W2A[4][2], W3A[4][2];
  f32x4 c2v[4], c3v[4];
  #pragma unroll
  for (int rt = 0; rt < 4; rt++){
    int g = rt*16 + ln15;
    #pragma unroll
    for (int kk = 0; kk < 2; kk++){
      W2A[rt][kk] = *(const half8*)&w2h[g*64 + kk*32 + quad*8];
      W3A[rt][kk] = *(const half8*)&w3h[g*64 + kk*32 + quad*8];
    }
    float4 cb2 = *(const float4*)&ws[WS_C2 + rt*16 + quad*4];
    float4 cb3 = *(const float4*)&ws[WS_C3 + rt*16 + quad*4];
    c2v[rt] = (f32x4){cb2.x, cb2.y, cb2.z, cb2.w};
    c3v[rt] = (f32x4){cb3.x, cb3.y, cb3.z, cb3.w};
  }
  // u[h] packed pairs for this lane's h-chunks
  unsigned int upk[2][4];
  #pragma unroll
  for (int kk = 0; kk < 2; kk++){
    float4 ua = *(const float4*)&ws[WS_U + kk*32 + quad*8];
    float4 ub = *(const float4*)&ws[WS_U + kk*32 + quad*8 + 4];
    upk[kk][0] = pkh2(ua.x, ua.y); upk[kk][1] = pkh2(ua.z, ua.w);
    upk[kk][2] = pkh2(ub.x, ub.y); upk[kk][3] = pkh2(ub.z, ub.w);
  }
  const unsigned short* A1H = (const unsigned short*)(ws + WS_A1) + (size_t)b*MM*64;
  int n = n0 + ln15;                                // this lane's n (shared by all waves)
  const unsigned short* cosP = (const unsigned short*)(ws + WS_COSH)
                               + (size_t)b*MM*NN + n;
  unsigned short* h2w = &h2W[w][0][0];

  f32x4 p[4];
  #pragma unroll
  for (int rt = 0; rt < 4; rt++) p[rt] = (f32x4){0.f,0.f,0.f,0.f};

  int m0i = ms*128 + w;
  unsigned int cu = cosP[(size_t)m0i*NN];
  uint4 a1a = *(const uint4*)&A1H[(size_t)m0i*64 + quad*8];
  uint4 a1b = *(const uint4*)&A1H[(size_t)m0i*64 + 32 + quad*8];

  for (int mc = 0; mc < 32; mc++){
    // prefetch next mc
    int mN = ms*128 + (mc < 31 ? (mc + 1) : 31)*4 + w;
    unsigned int cuN = cosP[(size_t)mN*NN];
    uint4 a1aN = *(const uint4*)&A1H[(size_t)mN*64 + quad*8];
    uint4 a1bN = *(const uint4*)&A1H[(size_t)mN*64 + 32 + quad*8];

    unsigned int cd = cu | (cu << 16);
    half2v ch = u2h(cd);
    uint4 q0, q1;
    q0.x = bh1(upk[0][0], ch, a1a.x); q0.y = bh1(upk[0][1], ch, a1a.y);
    q0.z = bh1(upk[0][2], ch, a1a.z); q0.w = bh1(upk[0][3], ch, a1a.w);
    q1.x = bh1(upk[1][0], ch, a1b.x); q1.y = bh1(upk[1][1], ch, a1b.y);
    q1.z = bh1(upk[1][2], ch, a1b.z); q1.w = bh1(upk[1][3], ch, a1b.w);
    half8 b0h = __builtin_bit_cast(half8, q0);
    half8 b1h = __builtin_bit_cast(half8, q1);

    // layer 2
    f32x4 acc[4];
    #pragma unroll
    for (int rt = 0; rt < 4; rt++){
      acc[rt] = __builtin_amdgcn_mfma_f32_16x16x32_f16(W2A[rt][0], b0h, c2v[rt], 0, 0, 0);
      acc[rt] = __builtin_amdgcn_mfma_f32_16x16x32_f16(W2A[rt][1], b1h, acc[rt], 0, 0, 0);
    }
    // relu + pack + h2 transpose write (g = rt*16 + quad*4 + r, row x = ln15)
    #pragma unroll
    for (int rt = 0; rt < 4; rt++){
      uint2 vv;
      vv.x = relu2(pkh2(acc[rt][0], acc[rt][1]));
      vv.y = relu2(pkh2(acc[rt][2], acc[rt][3]));
      *(uint2*)&h2w[ln15*72 + rt*16 + quad*4] = vv;
    }
    __asm__ volatile("s_waitcnt lgkmcnt(0)" ::: "memory");
    half8 e0 = *(const half8*)&h2w[ln15*72 + quad*8];
    half8 e1 = *(const half8*)&h2w[ln15*72 + 32 + quad*8];
    // layer 3 + running max (p seeded 0 => stored value = max(0, h3+c3) exactly)
    #pragma unroll
    for (int rt = 0; rt < 4; rt++){
      f32x4 a3 = __builtin_amdgcn_mfma_f32_16x16x32_f16(W3A[rt][0], e0, c3v[rt], 0, 0, 0);
      a3 = __builtin_amdgcn_mfma_f32_16x16x32_f16(W3A[rt][1], e1, a3, 0, 0, 0);
      #pragma unroll
      for (int r = 0; r < 4; r++) p[rt][r] = fmaxf(p[rt][r], a3[r]);
    }
    cu = cuN; a1a = a1aN; a1b = a1bN;
  }

  // 4-way cross-wave max combine: waves 1..3 park, wave 0 merges + stores.
  __syncthreads();
  if (w >= 1){
    #pragma unroll
    for (int rt = 0; rt < 4; rt++){
      f32x4 v = p[rt];
      *(float4*)&redS[w-1][ln15][rt*16 + quad*4] = make_float4(v[0], v[1], v[2], v[3]);
    }
  }
  __syncthreads();
  if (w == 0){
    float* Pb = Pp + (size_t)ms*PS + ((size_t)(b*NN + n) << 6);
    #pragma unroll
    for (int rt = 0; rt < 4; rt++){
      float4 o1 = *(const float4*)&redS[0][ln15][rt*16 + quad*4];
      float4 o2 = *(const float4*)&redS[1][ln15][rt*16 + quad*4];
      float4 o3 = *(const float4*)&redS[2][ln15][rt*16 + quad*4];
      float4 r4;
      r4.x = fmaxf(fmaxf(p[rt][0], o1.x), fmaxf(o2.x, o3.x));
      r4.y = fmaxf(fmaxf(p[rt][1], o1.y), fmaxf(o2.y, o3.y));
      r4.z = fmaxf(fmaxf(p[rt][2], o1.z), fmaxf(o2.z, o3.z));
      r4.w = fmaxf(fmaxf(p[rt][3], o1.w), fmaxf(o2.w, o3.w));
      *(float4*)&Pb[rt*16 + quad*4] = r4;
    }
  }
}

// ---------------- K4: tail (max 2 partials, Wc1f/relu, Wc2+bias) fp32 ----------------
__global__ __launch_bounds__(256) void k_tail(const float* Wc2, const float* bc2,
                                              const float* ws, float* out){
  __shared__ float WT[64][68];
  __shared__ float pT[32][68];
  __shared__ float cS[32][68];
  int t = threadIdx.x;
  int n0 = blockIdx.x * 32;
  int b = blockIdx.y;
  for (int i = t; i < 4096; i += 256) WT[i >> 6][i & 63] = ws[WS_WC1F + i];
  const float* P0 = ws + WS_P + ((size_t)(b*NN + n0) << 6);
  const float* P1 = P0 + PS;
  for (int i = t; i < 2048; i += 256) pT[i >> 6][i & 63] = fmaxf(P0[i], P1[i]);
  __syncthreads();
  {
    int n = t & 31, q = t >> 5;
    for (int k = 0; k < 8; k++){
      int g = q*8 + k;
      float acc = ws[WS_CC1 + g];
      for (int hs = 0; hs < 64; hs += 4){
        float4 wv = *(const float4*)&WT[g][hs];
        float4 pv = *(const float4*)&pT[n][hs];
        acc = dot4(wv, pv, acc);
      }
      cS[n][g] = fmaxf(acc, 0.f);
    }
  }
  __syncthreads();
  {
    int o = t & 127, hf = t >> 7;
    float bco = bc2[o];
    float accO[16];
    #pragma unroll
    for (int i = 0; i < 16; i++) accO[i] = bco;
    for (int hs = 0; hs < 64; hs += 4){
      float4 w4 = *(const float4*)&Wc2[o*64 + hs];
      #pragma unroll
      for (int i = 0; i < 16; i++){
        float4 cv = *(const float4*)&cS[hf*16 + i][hs];
        accO[i] = dot4(w4, cv, accO[i]);
      }
    }
    #pragma unroll
    for (int i = 0; i < 16; i++)
      out[((size_t)(b*OO + o))*NN + n0 + hf*16 + i] = accO[i];
  }
}

extern "C" void kernel_launch(void* const* d_in, const int* in_sizes, int n_in,
                              void* d_out, int out_size, void* d_ws, size_t ws_size,
                              hipStream_t stream){
  (void)in_sizes; (void)n_in; (void)out_size; (void)ws_size;
  const float* t_  = (const float*)d_in[0];
  const float* s_  = (const float*)d_in[1];
  const float* W1  = (const float*)d_in[2];
  const float* W2  = (const float*)d_in[3];
  const float* W3  = (const float*)d_in[4];
  const float* Wc1 = (const float*)d_in[5];
  const float* Wc2 = (const float*)d_in[6];
  const float* bc2 = (const float*)d_in[7];
  const float* g1 = (const float*)d_in[8],  *b1 = (const float*)d_in[9],
             * m1 = (const float*)d_in[10], *v1 = (const float*)d_in[11];
  const float* g2 = (const float*)d_in[12], *b2 = (const float*)d_in[13],
             * m2 = (const float*)d_in[14], *v2 = (const float*)d_in[15];
  const float* g3 = (const float*)d_in[16], *b3 = (const float*)d_in[17],
             * m3 = (const float*)d_in[18], *v3 = (const float*)d_in[19];
  const float* gc1 = (const float*)d_in[20], *bc1 = (const float*)d_in[21],
             * mc1 = (const float*)d_in[22], *vc1 = (const float*)d_in[23];
  float* ws = (float*)d_ws;
  float* out = (float*)d_out;

  k_prep<<<417, 256, 0, stream>>>(t_, s_, W1, W2, W3, Wc1,
      g1,b1,m1,v1, g2,b2,m2,v2, g3,b3,m3,v3, gc1,bc1,mc1,vc1, ws);
  k_cos<<<dim3(4, 16, 8), 256, 0, stream>>>(t_, s_, ws);
  k_main<<<dim3(64, 8, 2), 256, 0, stream>>>(ws, ws + WS_P);
  k_tail<<<dim3(32, 8), 256, 0, stream>>>(Wc2, bc2, ws, out);
}

// Round 5
// 168.720 us; speedup vs baseline: 1.5830x; 1.0857x over previous
//
#include <hip/hip_runtime.h>

// P2B_XCorr: B=8, F=128, M=256, N=1024, H=64, O=128. fp32 I/O.
// R13 = R12 + k_main serial-chain fix (R12 post-mortem: 3 rounds of occupancy
//   changes didn't move perf -> the stall is the per-wave in-loop LDS round
//   trip: pack -> write -> lgkmcnt(0) -> conflicted b128 read (~8-way, bank =
//   4*(ln15+quad) mod 32, 3.19M conflict cycles) -> MFMA, every iteration):
//   1) h2 tile re-laid [g4][c]: 16 rows x 136B, 8B cell per (g4=g/4, c=n).
//      Write (row 4rt+q, col c): banks 8rt+2(q+c) -> exactly 4/bank = b64
//      minimum (conflict-free). Read e-frag = 2x ds_read_b64 rows {2q,2q+1}
//      (fusable to ds_read2_b64): banks 4q+2c -> 4/bank = minimum.
//   2) software pipeline: L3 lags L2 by one m-iter. Order per iter:
//      read h2(mc-1) FIRST -> prefetch+h1+L2 (~150cyc) hides read latency ->
//      L3(mc-1)+fmax -> pack+write h2(mc) to buf[mc&1]. No asm waitcnt; the
//      compiler emits counted lgkmcnt (m97 evidence). Per-wave dbuf tile.
//   3) c3 deferred to store (R10-verified: p seeded -3e38, relu(p+c3) at end)
//      to free 12 regs for the extra in-flight state at the (256,3) cap.
// Frag layouts (HW-verified): A[m=lane&15][k=quad*8+j], B[k=quad*8+j][n=lane&15],
// D[row=quad*4+reg][col=lane&15].

#define BB 8
#define FF 128
#define MM 256
#define NN 1024
#define HH 64
#define OO 128
#define BN_EPS 1e-5f
#define COS_EPS 1e-8f

// ws layout (float offsets); total 2,251,008 floats = 8.59 MiB (proven envelope)
#define WS_U     0
#define WS_C2    64
#define WS_C3    128
#define WS_CC1   192
#define WS_W2H   256          // f16 [64][64] folded a2*W2 (2048 float slots)
#define WS_W3H   2304         // f16 [64][64] folded a3*W3 (2048 float slots)
#define WS_WC1F  8448
#define WS_A1    12544        // f16 A1H[b][m][64]
#define WS_NT    143616       // [b][m] fp32 (NS contiguous after)
#define WS_NS    145664       // [b][n] fp32
#define WS_COSH  153856       // f16 cos[b][m][n]
#define WS_P     1202432      // fp32 partials [2][b][n][64]
#define PS       524288

typedef _Float16 half2v __attribute__((ext_vector_type(2)));
typedef _Float16 half8  __attribute__((ext_vector_type(8)));
typedef __attribute__((ext_vector_type(4))) float f32x4;

__device__ __forceinline__ unsigned int pkh2(float a, float b){
  auto h = __builtin_amdgcn_cvt_pkrtz(a, b);
  return __builtin_bit_cast(unsigned int, h);
}
__device__ __forceinline__ half2v u2h(unsigned int u){
  return __builtin_bit_cast(half2v, u);
}
__device__ __forceinline__ unsigned int h2u(half2v v){
  return __builtin_bit_cast(unsigned int, v);
}
__device__ __forceinline__ unsigned int relu2(unsigned int d){
  half2v v = __builtin_elementwise_max(u2h(d), (half2v){(_Float16)0, (_Float16)0});
  return h2u(v);
}
__device__ __forceinline__ unsigned int bh1(unsigned int up, half2v c, unsigned int ap){
  half2v v = __builtin_elementwise_fma(u2h(up), c, u2h(ap));
  v = __builtin_elementwise_max(v, (half2v){(_Float16)0, (_Float16)0});
  return h2u(v);
}
__device__ __forceinline__ float dot4(float4 a, float4 b, float acc){
  acc = fmaf(a.x, b.x, acc); acc = fmaf(a.y, b.y, acc);
  acc = fmaf(a.z, b.z, acc); acc = fmaf(a.w, b.w, acc);
  return acc;
}

// ---------------- K1: prep (role-split: a1 | norms | fold) ----------------
__global__ __launch_bounds__(256) void k_prep(const float* t_, const float* s_,
    const float* W1, const float* W2, const float* W3, const float* Wc1,
    const float* g1, const float* b1, const float* m1, const float* v1,
    const float* g2, const float* b2, const float* m2, const float* v2,
    const float* g3, const float* b3, const float* m3, const float* v3,
    const float* gc1,const float* bc1,const float* mc1,const float* vc1,
    float* ws){
  __shared__ float W1s[64][133];
  int t = threadIdx.x;
  int bx = blockIdx.x;
  if (bx < 256){
    // ---- A1H[b][m][h] (f16) ----
    int b = bx >> 5, m0 = (bx & 31)*8;
    for (int idx = t; idx < 8192; idx += 256){
      int h = idx >> 7, f = idx & 127;
      W1s[h][f] = W1[h*129 + 1 + f];
    }
    __syncthreads();
    int h = t & 63, mg = t >> 6;
    const float* tp = t_ + (size_t)b*FF*MM + m0 + mg*2;
    float acc0 = 0.f, acc1 = 0.f;
    for (int f = 0; f < FF; f++){
      float wv = W1s[h][f];
      float2 tv = *(const float2*)&tp[(size_t)f*MM];
      acc0 = fmaf(wv, tv.x, acc0); acc1 = fmaf(wv, tv.y, acc1);
    }
    float a1 = g1[h] / sqrtf(v1[h] + BN_EPS);
    float c1 = b1[h] - a1*m1[h];
    unsigned short* dst = (unsigned short*)(ws + WS_A1) + ((size_t)(b*MM + m0 + mg*2))*64 + h;
    dst[0]  = (unsigned short)(pkh2(fmaf(a1, acc0, c1), 0.f) & 0xFFFFu);
    dst[64] = (unsigned short)(pkh2(fmaf(a1, acc1, c1), 0.f) & 0xFFFFu);
  } else if (bx < 416){
    // ---- norms ----
    __shared__ float red[4][64];
    int x = t & 63, fq = t >> 6;
    int idx = (bx - 256)*64 + x;
    const float* ptr; size_t stride;
    if (idx < BB*MM){
      int b = idx >> 8, m = idx & 255;
      ptr = t_ + (size_t)b*FF*MM + m; stride = MM;
    } else {
      int j = idx - BB*MM;
      int b = j >> 10, n = j & 1023;
      ptr = s_ + (size_t)b*FF*NN + n; stride = NN;
    }
    float acc = 0.f;
    for (int f = fq*32; f < fq*32 + 32; f++){
      float v = ptr[(size_t)f*stride]; acc = fmaf(v, v, acc);
    }
    red[fq][x] = acc;
    __syncthreads();
    if (fq == 0)
      ws[WS_NT + idx] = sqrtf(red[0][x] + red[1][x] + red[2][x] + red[3][x]);
  } else {
    // ---- fold ----
    if (t < 64){
      float a1 = g1[t] / sqrtf(v1[t] + BN_EPS);
      ws[WS_U + t]   = a1 * W1[t*129];
      float a2 = g2[t] / sqrtf(v2[t] + BN_EPS);
      ws[WS_C2 + t]  = b2[t] - a2*m2[t];
      float a3 = g3[t] / sqrtf(v3[t] + BN_EPS);
      ws[WS_C3 + t]  = b3[t] - a3*m3[t];
      float ac = gc1[t] / sqrtf(vc1[t] + BN_EPS);
      ws[WS_CC1 + t] = bc1[t] - ac*mc1[t];
    }
    unsigned short* w2h = (unsigned short*)(ws + WS_W2H);
    unsigned short* w3h = (unsigned short*)(ws + WS_W3H);
    for (int i = t; i < 4096; i += 256){
      int g = i >> 6;
      float a2 = g2[g] / sqrtf(v2[g] + BN_EPS);
      w2h[i] = __builtin_bit_cast(unsigned short, (_Float16)(a2 * W2[i]));
      float a3 = g3[g] / sqrtf(v3[g] + BN_EPS);
      w3h[i] = __builtin_bit_cast(unsigned short, (_Float16)(a3 * W3[i]));
      float ac = gc1[g] / sqrtf(vc1[g] + BN_EPS);
      ws[WS_WC1F + i] = ac * Wc1[i];
    }
  }
}

// ---------------- K2: cos via f16 MFMA. tile 64m x 64n ----------------
__global__ __launch_bounds__(256) void k_cos(const float* t_, const float* s_, float* ws){
  __shared__ __align__(16) unsigned short tS[64][136];
  __shared__ __align__(16) unsigned short sS[64][136];
  __shared__ float ntS[64], nsS[64];
  int t = threadIdx.x;
  int lane = t & 63, w = t >> 6;
  int ln15 = lane & 15, quad = lane >> 4;
  int m0 = blockIdx.x*64, n0 = blockIdx.y*64, b = blockIdx.z;
  {
    int x = t & 63;
    const float* tb = t_ + (size_t)b*FF*MM + m0 + x;
    const float* sb = s_ + (size_t)b*FF*NN + n0 + x;
    #pragma unroll
    for (int k = 0; k < 16; k++){
      int fp = w*16 + k;
      *(unsigned int*)&tS[x][2*fp] = pkh2(tb[(size_t)(2*fp)*MM], tb[(size_t)(2*fp+1)*MM]);
      *(unsigned int*)&sS[x][2*fp] = pkh2(sb[(size_t)(2*fp)*NN], sb[(size_t)(2*fp+1)*NN]);
    }
    if (t < 64) ntS[t] = ws[WS_NT + b*MM + m0 + t];
    else if (t < 128) nsS[t-64] = ws[WS_NS + b*NN + n0 + (t-64)];
  }
  __syncthreads();
  half8 A4[4];
  #pragma unroll
  for (int kc = 0; kc < 4; kc++)
    A4[kc] = *(const half8*)&tS[w*16 + ln15][kc*32 + quad*8];
  float4 nt4 = *(const float4*)&ntS[w*16 + quad*4];
  unsigned short* cosw = (unsigned short*)(ws + WS_COSH);
  #pragma unroll
  for (int ns = 0; ns < 4; ns++){
    f32x4 acc = (f32x4){0.f,0.f,0.f,0.f};
    #pragma unroll
    for (int kc = 0; kc < 4; kc++){
      half8 B4 = *(const half8*)&sS[ns*16 + ln15][kc*32 + quad*8];
      acc = __builtin_amdgcn_mfma_f32_16x16x32_f16(A4[kc], B4, acc, 0, 0, 0);
    }
    float nsv = nsS[ns*16 + ln15];
    int n = n0 + ns*16 + ln15;
    #pragma unroll
    for (int r = 0; r < 4; r++){
      int m = m0 + w*16 + quad*4 + r;
      float denom = fmaxf(nt4[r]*nsv, COS_EPS);
      float c = acc[r] * __builtin_amdgcn_rcpf(denom);
      cosw[(size_t)(b*MM + m)*NN + n] = (unsigned short)(pkh2(c, 0.f) & 0xFFFFu);
    }
  }
}

// ---------------- K3: main. grid (64,8,2), 4 waves; wave w: m = ms*128 + mc*4 + w ----------------
// h2 LDS tile per wave per buffer: [g4 row 0..15][c 0..15], cell = 8B (4 shorts),
// row stride 136B. Write row 4rt+quad col ln15; read e0 rows {2q,2q+1}, e1 +8.
__global__ __launch_bounds__(256, 3) void k_main(const float* ws, float* Pp){
  __shared__ __align__(16) unsigned char h2B[4][2][2176];  // 4 waves x dbuf x (16*136)
  __shared__ __align__(16) float redS[3][16][68];          // parked partials (waves 1..3)
  int t = threadIdx.x;
  int lane = t & 63, w = t >> 6;
  int ln15 = lane & 15, quad = lane >> 4;
  int b = blockIdx.y;
  int n0 = blockIdx.x * 16;
  int ms = blockIdx.z;

  // weight A-frags (prepacked f16 [g][k]) + layer-2 bias C-vectors (c3 deferred)
  const unsigned short* w2h = (const unsigned short*)(ws + WS_W2H);
  const unsigned short* w3h = (const unsigned short*)(ws + WS_W3H);
  half8 W2A[4][2], W3A[4][2];
  f32x4 c2v[4];
  #pragma unroll
  for (int rt = 0; rt < 4; rt++){
    int g = rt*16 + ln15;
    #pragma unroll
    for (int kk = 0; kk < 2; kk++){
      W2A[rt][kk] = *(const half8*)&w2h[g*64 + kk*32 + quad*8];
      W3A[rt][kk] = *(const half8*)&w3h[g*64 + kk*32 + quad*8];
    }
    float4 cb2 = *(const float4*)&ws[WS_C2 + rt*16 + quad*4];
    c2v[rt] = (f32x4){cb2.x, cb2.y, cb2.z, cb2.w};
  }
  f32x4 zf = (f32x4){0.f, 0.f, 0.f, 0.f};
  // u[h] packed pairs for this lane's h-chunks
  unsigned int upk[2][4];
  #pragma unroll
  for (int kk = 0; kk < 2; kk++){
    float4 ua = *(const float4*)&ws[WS_U + kk*32 + quad*8];
    float4 ub = *(const float4*)&ws[WS_U + kk*32 + quad*8 + 4];
    upk[kk][0] = pkh2(ua.x, ua.y); upk[kk][1] = pkh2(ua.z, ua.w);
    upk[kk][2] = pkh2(ub.x, ub.y); upk[kk][3] = pkh2(ub.z, ub.w);
  }
  const unsigned short* A1H = (const unsigned short*)(ws + WS_A1) + (size_t)b*MM*64;
  int n = n0 + ln15;                                // this lane's n (shared by all waves)
  const unsigned short* cosP = (const unsigned short*)(ws + WS_COSH)
                               + (size_t)b*MM*NN + n;
  unsigned char* myb = &h2B[w][0][0];
  int wOff = quad*136 + ln15*8;                     // write: + rt*544 (+ buf*2176)
  int rOff = quad*272 + ln15*8;                     // e0 lo; e0 hi +136; e1 +1088/+1224

  f32x4 p[4];
  #pragma unroll
  for (int rt = 0; rt < 4; rt++)
    p[rt] = (f32x4){-3.0e38f, -3.0e38f, -3.0e38f, -3.0e38f};

  int m0i = ms*128 + w;
  unsigned int cu = cosP[(size_t)m0i*NN];
  uint4 a1a = *(const uint4*)&A1H[(size_t)m0i*64 + quad*8];
  uint4 a1b = *(const uint4*)&A1H[(size_t)m0i*64 + 32 + quad*8];

  // ---- iter 0: L2 only, write buf0 ----
  {
    int mN = ms*128 + 4 + w;
    unsigned int cuN = cosP[(size_t)mN*NN];
    uint4 a1aN = *(const uint4*)&A1H[(size_t)mN*64 + quad*8];
    uint4 a1bN = *(const uint4*)&A1H[(size_t)mN*64 + 32 + quad*8];
    unsigned int cd = cu | (cu << 16);
    half2v ch = u2h(cd);
    uint4 q0, q1;
    q0.x = bh1(upk[0][0], ch, a1a.x); q0.y = bh1(upk[0][1], ch, a1a.y);
    q0.z = bh1(upk[0][2], ch, a1a.z); q0.w = bh1(upk[0][3], ch, a1a.w);
    q1.x = bh1(upk[1][0], ch, a1b.x); q1.y = bh1(upk[1][1], ch, a1b.y);
    q1.z = bh1(upk[1][2], ch, a1b.z); q1.w = bh1(upk[1][3], ch, a1b.w);
    half8 b0h = __builtin_bit_cast(half8, q0);
    half8 b1h = __builtin_bit_cast(half8, q1);
    f32x4 acc[4];
    #pragma unroll
    for (int rt = 0; rt < 4; rt++){
      acc[rt] = __builtin_amdgcn_mfma_f32_16x16x32_f16(W2A[rt][0], b0h, c2v[rt], 0, 0, 0);
      acc[rt] = __builtin_amdgcn_mfma_f32_16x16x32_f16(W2A[rt][1], b1h, acc[rt], 0, 0, 0);
    }
    #pragma unroll
    for (int rt = 0; rt < 4; rt++){
      uint2 vv;
      vv.x = relu2(pkh2(acc[rt][0], acc[rt][1]));
      vv.y = relu2(pkh2(acc[rt][2], acc[rt][3]));
      *(uint2*)(myb + rt*544 + wOff) = vv;
    }
    cu = cuN; a1a = a1aN; a1b = a1bN;
  }

  // ---- iters 1..31: read h2(mc-1), L2(mc), L3(mc-1), write h2(mc) ----
  for (int mc = 1; mc < 32; mc++){
    unsigned char* rb = myb + ((mc - 1) & 1)*2176;
    uint2 e0l = *(const uint2*)(rb + rOff);
    uint2 e0h = *(const uint2*)(rb + rOff + 136);
    uint2 e1l = *(const uint2*)(rb + rOff + 1088);
    uint2 e1h = *(const uint2*)(rb + rOff + 1224);

    int mN = ms*128 + (mc < 31 ? mc + 1 : 31)*4 + w;
    unsigned int cuN = cosP[(size_t)mN*NN];
    uint4 a1aN = *(const uint4*)&A1H[(size_t)mN*64 + quad*8];
    uint4 a1bN = *(const uint4*)&A1H[(size_t)mN*64 + 32 + quad*8];

    unsigned int cd = cu | (cu << 16);
    half2v ch = u2h(cd);
    uint4 q0, q1;
    q0.x = bh1(upk[0][0], ch, a1a.x); q0.y = bh1(upk[0][1], ch, a1a.y);
    q0.z = bh1(upk[0][2], ch, a1a.z); q0.w = bh1(upk[0][3], ch, a1a.w);
    q1.x = bh1(upk[1][0], ch, a1b.x); q1.y = bh1(upk[1][1], ch, a1b.y);
    q1.z = bh1(upk[1][2], ch, a1b.z); q1.w = bh1(upk[1][3], ch, a1b.w);
    half8 b0h = __builtin_bit_cast(half8, q0);
    half8 b1h = __builtin_bit_cast(half8, q1);

    f32x4 acc[4];
    #pragma unroll
    for (int rt = 0; rt < 4; rt++){
      acc[rt] = __builtin_amdgcn_mfma_f32_16x16x32_f16(W2A[rt][0], b0h, c2v[rt], 0, 0, 0);
      acc[rt] = __builtin_amdgcn_mfma_f32_16x16x32_f16(W2A[rt][1], b1h, acc[rt], 0, 0, 0);
    }

    // L3 on prev iter's h2 (reads issued at loop top; latency hidden by h1+L2)
    uint4 ue0 = make_uint4(e0l.x, e0l.y, e0h.x, e0h.y);
    uint4 ue1 = make_uint4(e1l.x, e1l.y, e1h.x, e1h.y);
    half8 pe0 = __builtin_bit_cast(half8, ue0);
    half8 pe1 = __builtin_bit_cast(half8, ue1);
    #pragma unroll
    for (int rt = 0; rt < 4; rt++){
      f32x4 a3 = __builtin_amdgcn_mfma_f32_16x16x32_f16(W3A[rt][0], pe0, zf, 0, 0, 0);
      a3 = __builtin_amdgcn_mfma_f32_16x16x32_f16(W3A[rt][1], pe1, a3, 0, 0, 0);
      #pragma unroll
      for (int r = 0; r < 4; r++) p[rt][r] = fmaxf(p[rt][r], a3[r]);
    }

    // pack + write h2(mc)
    unsigned char* wb = myb + (mc & 1)*2176;
    #pragma unroll
    for (int rt = 0; rt < 4; rt++){
      uint2 vv;
      vv.x = relu2(pkh2(acc[rt][0], acc[rt][1]));
      vv.y = relu2(pkh2(acc[rt][2], acc[rt][3]));
      *(uint2*)(wb + rt*544 + wOff) = vv;
    }
    cu = cuN; a1a = a1aN; a1b = a1bN;
  }

  // ---- epilogue: L3 of iter 31 ----
  {
    unsigned char* rb = myb + 2176;  // buf[31&1]
    uint2 e0l = *(const uint2*)(rb + rOff);
    uint2 e0h = *(const uint2*)(rb + rOff + 136);
    uint2 e1l = *(const uint2*)(rb + rOff + 1088);
    uint2 e1h = *(const uint2*)(rb + rOff + 1224);
    uint4 ue0 = make_uint4(e0l.x, e0l.y, e0h.x, e0h.y);
    uint4 ue1 = make_uint4(e1l.x, e1l.y, e1h.x, e1h.y);
    half8 pe0 = __builtin_bit_cast(half8, ue0);
    half8 pe1 = __builtin_bit_cast(half8, ue1);
    #pragma unroll
    for (int rt = 0; rt < 4; rt++){
      f32x4 a3 = __builtin_amdgcn_mfma_f32_16x16x32_f16(W3A[rt][0], pe0, zf, 0, 0, 0);
      a3 = __builtin_amdgcn_mfma_f32_16x16x32_f16(W3A[rt][1], pe1, a3, 0, 0, 0);
      #pragma unroll
      for (int r = 0; r < 4; r++) p[rt][r] = fmaxf(p[rt][r], a3[r]);
    }
  }

  // 4-way cross-wave max combine: waves 1..3 park raw p, wave 0 merges,
  // applies deferred c3 + relu, stores.
  __syncthreads();
  if (w >= 1){
    #pragma unroll
    for (int rt = 0; rt < 4; rt++){
      f32x4 v = p[rt];
      *(float4*)&redS[w-1][ln15][rt*16 + quad*4] = make_float4(v[0], v[1], v[2], v[3]);
    }
  }
  __syncthreads();
  if (w == 0){
    float* Pb = Pp + (size_t)ms*PS + ((size_t)(b*NN + n) << 6);
    #pragma unroll
    for (int rt = 0; rt < 4; rt++){
      float4 o1 = *(const float4*)&redS[0][ln15][rt*16 + quad*4];
      float4 o2 = *(const float4*)&redS[1][ln15][rt*16 + quad*4];
      float4 o3 = *(const float4*)&redS[2][ln15][rt*16 + quad*4];
      float4 c3b = *(const float4*)&ws[WS_C3 + rt*16 + quad*4];
      float4 r4;
      r4.x = fmaxf(fmaxf(fmaxf(p[rt][0], o1.x), fmaxf(o2.x, o3.x)) + c3b.x, 0.f);
      r4.y = fmaxf(fmaxf(fmaxf(p[rt][1], o1.y), fmaxf(o2.y, o3.y)) + c3b.y, 0.f);
      r4.z = fmaxf(fmaxf(fmaxf(p[rt][2], o1.z), fmaxf(o2.z, o3.z)) + c3b.z, 0.f);
      r4.w = fmaxf(fmaxf(fmaxf(p[rt][3], o1.w), fmaxf(o2.w, o3.w)) + c3b.w, 0.f);
      *(float4*)&Pb[rt*16 + quad*4] = r4;
    }
  }
}

// ---------------- K4: tail (max 2 partials, Wc1f/relu, Wc2+bias) fp32 ----------------
__global__ __launch_bounds__(256) void k_tail(const float* Wc2, const float* bc2,
                                              const float* ws, float* out){
  __shared__ float WT[64][68];
  __shared__ float pT[32][68];
  __shared__ float cS[32][68];
  int t = threadIdx.x;
  int n0 = blockIdx.x * 32;
  int b = blockIdx.y;
  for (int i = t; i < 4096; i += 256) WT[i >> 6][i & 63] = ws[WS_WC1F + i];
  const float* P0 = ws + WS_P + ((size_t)(b*NN + n0) << 6);
  const float* P1 = P0 + PS;
  for (int i = t; i < 2048; i += 256) pT[i >> 6][i & 63] = fmaxf(P0[i], P1[i]);
  __syncthreads();
  {
    int n = t & 31, q = t >> 5;
    for (int k = 0; k < 8; k++){
      int g = q*8 + k;
      float acc = ws[WS_CC1 + g];
      for (int hs = 0; hs < 64; hs += 4){
        float4 wv = *(const float4*)&WT[g][hs];
        float4 pv = *(const float4*)&pT[n][hs];
        acc = dot4(wv, pv, acc);
      }
      cS[n][g] = fmaxf(acc, 0.f);
    }
  }
  __syncthreads();
  {
    int o = t & 127, hf = t >> 7;
    float bco = bc2[o];
    float accO[16];
    #pragma unroll
    for (int i = 0; i < 16; i++) accO[i] = bco;
    for (int hs = 0; hs < 64; hs += 4){
      float4 w4 = *(const float4*)&Wc2[o*64 + hs];
      #pragma unroll
      for (int i = 0; i < 16; i++){
        float4 cv = *(const float4*)&cS[hf*16 + i][hs];
        accO[i] = dot4(w4, cv, accO[i]);
      }
    }
    #pragma unroll
    for (int i = 0; i < 16; i++)
      out[((size_t)(b*OO + o))*NN + n0 + hf*16 + i] = accO[i];
  }
}

extern "C" void kernel_launch(void* const* d_in, const int* in_sizes, int n_in,
                              void* d_out, int out_size, void* d_ws, size_t ws_size,
                              hipStream_t stream){
  (void)in_sizes; (void)n_in; (void)out_size; (void)ws_size;
  const float* t_  = (const float*)d_in[0];
  const float* s_  = (const float*)d_in[1];
  const float* W1  = (const float*)d_in[2];
  const float* W2  = (const float*)d_in[3];
  const float* W3  = (const float*)d_in[4];
  const float* Wc1 = (const float*)d_in[5];
  const float* Wc2 = (const float*)d_in[6];
  const float* bc2 = (const float*)d_in[7];
  const float* g1 = (const float*)d_in[8],  *b1 = (const float*)d_in[9],
             * m1 = (const float*)d_in[10], *v1 = (const float*)d_in[11];
  const float* g2 = (const float*)d_in[12], *b2 = (const float*)d_in[13],
             * m2 = (const float*)d_in[14], *v2 = (const float*)d_in[15];
  const float* g3 = (const float*)d_in[16], *b3 = (const float*)d_in[17],
             * m3 = (const float*)d_in[18], *v3 = (const float*)d_in[19];
  const float* gc1 = (const float*)d_in[20], *bc1 = (const float*)d_in[21],
             * mc1 = (const float*)d_in[22], *vc1 = (const float*)d_in[23];
  float* ws = (float*)d_ws;
  float* out = (float*)d_out;

  k_prep<<<417, 256, 0, stream>>>(t_, s_, W1, W2, W3, Wc1,
      g1,b1,m1,v1, g2,b2,m2,v2, g3,b3,m3,v3, gc1,bc1,mc1,vc1, ws);
  k_cos<<<dim3(4, 16, 8), 256, 0, stream>>>(t_, s_, ws);
  k_main<<<dim3(64, 8, 2), 256, 0, stream>>>(ws, ws + WS_P);
  k_tail<<<dim3(32, 8), 256, 0, stream>>>(Wc2, bc2, ws, out);
}